// Round 5
// baseline (340.827 us; speedup 1.0000x reference)
//
#include <hip/hip_runtime.h>
#include <hip/hip_bf16.h>
#include <math.h>

#define N_NODES 16384
#define E_EDGES 131072
#define ETOT (E_EDGES + N_NODES)   // 147456 (self-loops appended)
#define BGRAPH 256
#define F_INPUT 78
#define KPAD1 96                   // F_INPUT padded to mult of 32
#define HID 128
#define HEADS 10
#define F1 (HEADS * HID)           // 1280
#define NPAD1 1408                 // 1280 H-cols + es(1280..1289) + ed(1296..1305) + pad
#define NPAD2 160                  // 128 H-cols + es2(128) + ed2(129) + pad
#define F_CELL 954
#define KPADC 960                  // F_CELL padded
#define NEG_SLOPE 0.2f

typedef __attribute__((ext_vector_type(8))) short frag_t;   // 8 bf16
typedef __attribute__((ext_vector_type(4))) float f4_t;
typedef __attribute__((ext_vector_type(8))) unsigned short u16x8;

static __device__ __forceinline__ unsigned fkey(float f) {
    unsigned b = __float_as_uint(f);
    return (b & 0x80000000u) ? ~b : (b | 0x80000000u);
}
static __device__ __forceinline__ float funkey(unsigned k) {
    unsigned b = (k & 0x80000000u) ? (k ^ 0x80000000u) : ~k;
    return __uint_as_float(b);
}
static __device__ __forceinline__ unsigned short f2bf(float f) {
    __hip_bfloat16 h = __float2bfloat16(f);
    return *(unsigned short*)&h;
}
static __device__ __forceinline__ float bf2f(unsigned short u) {
    return __uint_as_float(((unsigned)u) << 16);
}

// ================= MFMA bf16 GEMM (generalized) =================
// A [M,Kpad] bf16, BT [N,Kpad] bf16. C row-major [M,N].
// BM = 32*WM16, BN = 32*WN16 (2x2 wave grid). Fused bias+ReLU epilogue.
template<int WM16, int WN16, int OUT_BF16, int ACT, int HAS_BIAS>
__global__ __launch_bounds__(256) void mfma_gemm(
    const unsigned short* __restrict__ A, const unsigned short* __restrict__ BT,
    const float* __restrict__ bias, void* __restrict__ C,
    int M, int N, int Kpad)
{
    constexpr int BM = 32 * WM16, BN = 32 * WN16;
    __shared__ __align__(16) unsigned short Als[BM * 32];
    __shared__ __align__(16) unsigned short Bls[BN * 32];
    const int t = threadIdx.x;
    const int wave = t >> 6, lane = t & 63;
    const int wr = (wave >> 1) * (16 * WM16);
    const int wc = (wave & 1) * (16 * WN16);
    const int row0 = blockIdx.y * BM;
    const int col0 = blockIdx.x * BN;

    f4_t acc[WM16][WN16];
#pragma unroll
    for (int m = 0; m < WM16; m++)
#pragma unroll
        for (int n = 0; n < WN16; n++) { acc[m][n] = (f4_t){0.f, 0.f, 0.f, 0.f}; }

    const int lrow = lane & 15, kg = lane >> 4;
    for (int kk = 0; kk < Kpad; kk += 32) {
        for (int i = t; i < BM * 4; i += 256) {
            int r = i >> 2, slot = i & 3;
            uint4 v = *(const uint4*)&A[(size_t)(row0 + r) * Kpad + kk + slot * 8];
            *(uint4*)&Als[r * 32 + ((slot ^ (r & 3) ^ ((r >> 2) & 3)) * 8)] = v;
        }
        for (int i = t; i < BN * 4; i += 256) {
            int r = i >> 2, slot = i & 3;
            uint4 v = *(const uint4*)&BT[(size_t)(col0 + r) * Kpad + kk + slot * 8];
            *(uint4*)&Bls[r * 32 + ((slot ^ (r & 3) ^ ((r >> 2) & 3)) * 8)] = v;
        }
        __syncthreads();
        frag_t af[WM16], bfr[WN16];
#pragma unroll
        for (int m = 0; m < WM16; m++) {
            int r = wr + m * 16 + lrow;
            af[m] = *(frag_t*)&Als[r * 32 + ((kg ^ (r & 3) ^ ((r >> 2) & 3)) * 8)];
        }
#pragma unroll
        for (int n = 0; n < WN16; n++) {
            int r = wc + n * 16 + lrow;
            bfr[n] = *(frag_t*)&Bls[r * 32 + ((kg ^ (r & 3) ^ ((r >> 2) & 3)) * 8)];
        }
#pragma unroll
        for (int m = 0; m < WM16; m++)
#pragma unroll
            for (int n = 0; n < WN16; n++)
                acc[m][n] = __builtin_amdgcn_mfma_f32_16x16x32_bf16(af[m], bfr[n], acc[m][n], 0, 0, 0);
        __syncthreads();
    }

#pragma unroll
    for (int m = 0; m < WM16; m++) {
#pragma unroll
        for (int n = 0; n < WN16; n++) {
            int col = col0 + wc + n * 16 + lrow;
            float bv = HAS_BIAS ? bias[col] : 0.f;
#pragma unroll
            for (int r = 0; r < 4; r++) {
                int row = row0 + wr + m * 16 + kg * 4 + r;
                float v = acc[m][n][r] + bv;
                if (ACT) v = fmaxf(v, 0.f);
                if (OUT_BF16) ((unsigned short*)C)[(size_t)row * N + col] = f2bf(v);
                else          ((float*)C)[(size_t)row * N + col] = v;
            }
        }
    }
}

// ================= mega weight-prep (all transposes/conversions, 1 kernel) ====
#define S0 1572864   // xb: 16384*96
#define S1 135168    // W1T: 1408*96
#define S2 204800    // W2T: 160*1280
#define S3 1966080   // Wf1T: 2048*960
#define S4 1048576   // Wf2T: 512*2048
#define S5 65536     // Wf3T: 128*512
#define S6 16384     // WgT: 128*128
#define PREP_TOTAL (S0+S1+S2+S3+S4+S5+S6)   // 5009408 = 19568*256

__global__ void prep_weights(const float* __restrict__ x,  const float* __restrict__ W1,
                             const float* __restrict__ W2, const float* __restrict__ Wf1,
                             const float* __restrict__ Wf2, const float* __restrict__ Wf3,
                             const float* __restrict__ Wg,
                             unsigned short* __restrict__ xb,  unsigned short* __restrict__ W1T,
                             unsigned short* __restrict__ W2T, unsigned short* __restrict__ Wf1T,
                             unsigned short* __restrict__ Wf2T, unsigned short* __restrict__ Wf3T,
                             unsigned short* __restrict__ WgT)
{
    int i = blockIdx.x * 256 + threadIdx.x;
    if (i < S0) { int r = i / 96, k = i % 96;
        xb[i] = (k < F_INPUT) ? f2bf(x[r * F_INPUT + k]) : 0; return; }
    i -= S0;
    if (i < S1) { int n = i / 96, k = i % 96;
        W1T[i] = (n < F1 && k < F_INPUT) ? f2bf(W1[(size_t)k * F1 + n]) : 0; return; }
    i -= S1;
    if (i < S2) { int n = i / 1280, k = i % 1280;
        W2T[i] = (n < HID) ? f2bf(W2[(size_t)k * HID + n]) : 0; return; }
    i -= S2;
    if (i < S3) { int n = i / 960, k = i % 960;
        Wf1T[i] = (k < F_CELL) ? f2bf(Wf1[(size_t)k * 2048 + n]) : 0; return; }
    i -= S3;
    if (i < S4) { int n = i / 2048, k = i % 2048;
        Wf2T[i] = f2bf(Wf2[(size_t)k * 512 + n]); return; }
    i -= S4;
    if (i < S5) { int n = i / 512, k = i % 512;
        Wf3T[i] = f2bf(Wf3[(size_t)k * HID + n]); return; }
    i -= S5;
    { int n = i / 128, k = i % 128;
        WgT[i] = f2bf(Wg[(size_t)k * HID + n]); }
}

// fold1: W1T rows 1280+sd*16+h = per-head a-fold of W1 (es rows 1280.., ed rows 1296..)
__global__ void fold_a1(const float* __restrict__ W1, const float* __restrict__ as_,
                        const float* __restrict__ ad_, unsigned short* __restrict__ W1T)
{
    int b = blockIdx.x;           // 0..19
    int sd = b / HEADS, h = b % HEADS, l = threadIdx.x;  // 64 lanes
    const float* a = (sd ? ad_ : as_) + h * HID;
    float2 av = *(const float2*)&a[2 * l];
    int row = 1280 + sd * 16 + h;
    for (int k = 0; k < F_INPUT; k++) {
        float2 wv = *(const float2*)&W1[(size_t)k * F1 + h * HID + 2 * l];
        float p = wv.x * av.x + wv.y * av.y;
#pragma unroll
        for (int o = 32; o > 0; o >>= 1) p += __shfl_xor(p, o);
        if (l == 0) W1T[(size_t)row * KPAD1 + k] = f2bf(p);
    }
}

// fold2: W2T rows 128 (es2) / 129 (ed2) = W2 @ a2
__global__ void fold_a2(const float* __restrict__ W2, const float* __restrict__ as_,
                        const float* __restrict__ ad_, unsigned short* __restrict__ W2T)
{
    int tid = blockIdx.x * 256 + threadIdx.x;
    if (tid >= 2 * F1) return;
    int k = tid >> 1, sd = tid & 1;
    const float* a = sd ? ad_ : as_;
    float s = 0.f;
    for (int c = 0; c < HID; c++) s += W2[(size_t)k * HID + c] * a[c];
    W2T[(size_t)(128 + sd) * F1 + k] = f2bf(s);
}

// ================= CSR build (by dst) =================
__global__ void hist_dst(const int* __restrict__ ei, int* __restrict__ counts)
{
    int e = blockIdx.x * blockDim.x + threadIdx.x;
    if (e >= ETOT) return;
    int dst = (e < E_EDGES) ? ei[E_EDGES + e] : (e - E_EDGES);
    atomicAdd(&counts[dst], 1);
}

__global__ void scan_counts(const int* __restrict__ counts,
                            int* __restrict__ row_start, int* __restrict__ cursor)
{
    __shared__ int part[256];
    int t = threadIdx.x;
    int base = t * 64;
    int sum = 0;
    for (int i = 0; i < 64; i++) sum += counts[base + i];
    part[t] = sum;
    __syncthreads();
    for (int o = 1; o < 256; o <<= 1) {
        int v = 0;
        if (t >= o) v = part[t - o];
        __syncthreads();
        part[t] += v;
        __syncthreads();
    }
    int run = (t == 0) ? 0 : part[t - 1];
    for (int i = 0; i < 64; i++) {
        row_start[base + i] = run;
        cursor[base + i] = run;
        run += counts[base + i];
    }
    if (t == 255) row_start[N_NODES] = run;
}

__global__ void scatter_csr(const int* __restrict__ ei, int* __restrict__ cursor,
                            int* __restrict__ csr_src)
{
    int e = blockIdx.x * blockDim.x + threadIdx.x;
    if (e >= ETOT) return;
    int src, dst;
    if (e < E_EDGES) { src = ei[e]; dst = ei[E_EDGES + e]; } else { src = dst = e - E_EDGES; }
    int pos = atomicAdd(&cursor[dst], 1);
    csr_src[pos] = src;
}

// ================= GAT layer-1 aggregation: WAVE per dst, single-pass =========
// H [N, NPAD1] bf16: cols 0..1279 = h, 1280..1289 = es, 1296..1305 = ed.
// Online softmax: first 64-edge chunk gives max directly; >64 deg rescales.
__global__ __launch_bounds__(256) void gat1_agg(
    const int* __restrict__ row_start, const int* __restrict__ csr_src,
    const unsigned short* __restrict__ H,
    const float* __restrict__ b, unsigned short* __restrict__ xout)
{
    const int w = threadIdx.x >> 6, l = threadIdx.x & 63;
    const int n = blockIdx.x * 4 + w;
    const int rs = row_start[n];
    const int deg = row_start[n + 1] - rs;
    const int hi = l >> 4;

    __shared__ float w_lds[4][64][11];
    __shared__ int   src_lds[4][64];

    // ed of own node from its H row
    const unsigned short* rowN = H + (size_t)n * NPAD1;
    float edv[HEADS];
    {
        u16x8 e8 = *(const u16x8*)&rowN[1296];
        unsigned e2 = *(const unsigned*)&rowN[1304];
#pragma unroll
        for (int h = 0; h < 8; h++) edv[h] = bf2f((unsigned short)e8[h]);
        edv[8] = bf2f((unsigned short)(e2 & 0xffffu));
        edv[9] = bf2f((unsigned short)(e2 >> 16));
    }

    float m[HEADS], den[HEADS], acc[3][8];
#pragma unroll
    for (int h = 0; h < HEADS; h++) den[h] = 0.f;
#pragma unroll
    for (int s0 = 0; s0 < 3; s0++)
#pragma unroll
        for (int k = 0; k < 8; k++) acc[s0][k] = 0.f;

    for (int base = 0; base < deg; base += 64) {
        int e = base + l;
        bool act = e < deg;
        int s = 0;
        float v[HEADS];
        if (act) {
            s = csr_src[rs + e];
            const unsigned short* rsrc = H + (size_t)s * NPAD1 + 1280;
            u16x8 e8 = *(const u16x8*)rsrc;
            unsigned e2 = *(const unsigned*)(rsrc + 8);
            float esv[HEADS];
#pragma unroll
            for (int h = 0; h < 8; h++) esv[h] = bf2f((unsigned short)e8[h]);
            esv[8] = bf2f((unsigned short)(e2 & 0xffffu));
            esv[9] = bf2f((unsigned short)(e2 >> 16));
#pragma unroll
            for (int h = 0; h < HEADS; h++) {
                float t_ = esv[h] + edv[h];
                v[h] = (t_ >= 0.f) ? t_ : NEG_SLOPE * t_;
            }
        } else {
#pragma unroll
            for (int h = 0; h < HEADS; h++) v[h] = -INFINITY;
        }
        // chunk max
        float cm[HEADS];
#pragma unroll
        for (int h = 0; h < HEADS; h++) {
            cm[h] = v[h];
#pragma unroll
            for (int o = 32; o > 0; o >>= 1) cm[h] = fmaxf(cm[h], __shfl_xor(cm[h], o));
        }
        if (base == 0) {
#pragma unroll
            for (int h = 0; h < HEADS; h++) m[h] = cm[h];
        } else {   // rare: online rescale
            float sc[HEADS];
#pragma unroll
            for (int h = 0; h < HEADS; h++) {
                float mn = fmaxf(m[h], cm[h]);
                sc[h] = __expf(m[h] - mn);
                m[h] = mn;
                den[h] *= sc[h];
            }
#pragma unroll
            for (int slot = 0; slot < 3; slot++) {
                float s_ = (slot == 2) ? ((hi & 1) ? sc[9] : sc[8])
                         : (hi == 0 ? sc[slot * 4] : hi == 1 ? sc[slot * 4 + 1]
                          : hi == 2 ? sc[slot * 4 + 2] : sc[slot * 4 + 3]);
#pragma unroll
                for (int k = 0; k < 8; k++) acc[slot][k] *= s_;
            }
        }
        float wv[HEADS];
#pragma unroll
        for (int h = 0; h < HEADS; h++) {
            wv[h] = act ? __expf(v[h] - m[h]) : 0.f;
            den[h] += wv[h];
            w_lds[w][l][h] = wv[h];
        }
        src_lds[w][l] = s;
        asm volatile("" ::: "memory");

        int cnt = min(64, deg - base);
        for (int j = 0; j < cnt; j++) {
            int sj = src_lds[w][j];
            const unsigned short* hrow = H + (size_t)sj * NPAD1;
#pragma unroll
            for (int slot = 0; slot < 3; slot++) {
                if (slot < 2 || l < 32) {
                    int c0 = slot * 512 + l * 8;
                    float wj = w_lds[w][j][slot * 4 + hi];
                    u16x8 hv = *(const u16x8*)&hrow[c0];
#pragma unroll
                    for (int k = 0; k < 8; k++)
                        acc[slot][k] = fmaf(wj, bf2f((unsigned short)hv[k]), acc[slot][k]);
                }
            }
        }
        asm volatile("" ::: "memory");
    }

#pragma unroll
    for (int h = 0; h < HEADS; h++)
#pragma unroll
        for (int o = 32; o > 0; o >>= 1) den[h] += __shfl_xor(den[h], o);

    unsigned short* orow = xout + (size_t)n * F1;
#pragma unroll
    for (int slot = 0; slot < 3; slot++) {
        if (slot < 2 || l < 32) {
            int c0 = slot * 512 + l * 8;
            float dh = (slot == 2) ? ((hi & 1) ? den[9] : den[8])
                     : (hi == 0 ? den[slot * 4] : hi == 1 ? den[slot * 4 + 1]
                      : hi == 2 ? den[slot * 4 + 2] : den[slot * 4 + 3]);
            float inv = 1.f / dh;
            float4 b0 = *(const float4*)&b[c0];
            float4 b1 = *(const float4*)&b[c0 + 4];
            float bb[8] = {b0.x, b0.y, b0.z, b0.w, b1.x, b1.y, b1.z, b1.w};
            u16x8 ov;
#pragma unroll
            for (int k = 0; k < 8; k++) {
                float v = acc[slot][k] * inv + bb[k];
                ov[k] = f2bf((v > 0.f) ? v : expm1f(v));
            }
            *(u16x8*)&orow[c0] = ov;
        }
    }
}

// ================= GAT layer-2 aggregation: WAVE per dst, single-pass =========
// H2 [N, NPAD2] bf16: cols 0..127 = h, 128 = es2, 129 = ed2.
__global__ __launch_bounds__(256) void gat2_agg(
    const int* __restrict__ row_start, const int* __restrict__ csr_src,
    const unsigned short* __restrict__ H2,
    const float* __restrict__ b, float* __restrict__ xout)
{
    const int w = threadIdx.x >> 6, l = threadIdx.x & 63;
    const int n = blockIdx.x * 4 + w;
    const int rs = row_start[n];
    const int deg = row_start[n + 1] - rs;
    const float edv = bf2f((unsigned short)((*(const unsigned*)&H2[(size_t)n * NPAD2 + 128]) >> 16));

    float m = 0.f, den = 0.f;
    float2 acc = {0.f, 0.f};
    for (int base = 0; base < deg; base += 64) {
        int e = base + l;
        bool act = e < deg;
        int s = 0;
        float v = -INFINITY;
        if (act) {
            s = csr_src[rs + e];
            unsigned p = *(const unsigned*)&H2[(size_t)s * NPAD2 + 128];
            float t_ = bf2f((unsigned short)(p & 0xffffu)) + edv;
            v = (t_ >= 0.f) ? t_ : NEG_SLOPE * t_;
        }
        float cm = v;
#pragma unroll
        for (int o = 32; o > 0; o >>= 1) cm = fmaxf(cm, __shfl_xor(cm, o));
        if (base == 0) m = cm;
        else {
            float mn = fmaxf(m, cm);
            float sc = __expf(m - mn);
            m = mn; den *= sc; acc.x *= sc; acc.y *= sc;
        }
        float wv = act ? __expf(v - m) : 0.f;
        den += wv;
        int cnt = min(64, deg - base);
        for (int j = 0; j < cnt; j++) {
            float wj = __shfl(wv, j);
            int   sj = __shfl(s, j);
            unsigned hp = *(const unsigned*)&H2[(size_t)sj * NPAD2 + 2 * l];
            acc.x = fmaf(wj, bf2f((unsigned short)(hp & 0xffffu)), acc.x);
            acc.y = fmaf(wj, bf2f((unsigned short)(hp >> 16)), acc.y);
        }
    }
#pragma unroll
    for (int o = 32; o > 0; o >>= 1) den += __shfl_xor(den, o);

    float inv = 1.f / den;
    float2 bv = *(const float2*)&b[2 * l];
    float v0 = acc.x * inv + bv.x;
    float v1 = acc.y * inv + bv.y;
    float2 ov;
    ov.x = (v0 > 0.f) ? v0 : expm1f(v0);
    ov.y = (v1 > 0.f) ? v1 : expm1f(v1);
    *(float2*)(xout + (size_t)n * HID + 2 * l) = ov;
}

// ================= pool / cell / final =================
__global__ void pool_max(const float* __restrict__ x2, const int* __restrict__ batch,
                         unsigned* __restrict__ pk)
{
    int idx = blockIdx.x * blockDim.x + threadIdx.x;
    if (idx >= N_NODES * HID) return;
    int n = idx >> 7, c = idx & 127;
    atomicMax(&pk[batch[n] * HID + c], fkey(x2[idx]));
}

__global__ void decode_keys_bf16(const unsigned* __restrict__ pk,
                                 unsigned short* __restrict__ outb, int count)
{
    int i = blockIdx.x * blockDim.x + threadIdx.x;
    if (i < count) outb[i] = f2bf(funkey(pk[i]));
}

__global__ void cell_norm(const float* __restrict__ cell, unsigned short* __restrict__ celln)
{
    int b = blockIdx.x;     // 256 rows
    int t = threadIdx.x;    // 256 threads
    __shared__ float red[256];
    float s = 0.f;
    for (int c = t; c < F_CELL; c += 256) { float v = cell[(size_t)b * F_CELL + c]; s += v * v; }
    red[t] = s; __syncthreads();
    for (int o = 128; o > 0; o >>= 1) { if (t < o) red[t] += red[t + o]; __syncthreads(); }
    float inv = 1.f / fmaxf(sqrtf(red[0]), 1e-12f);
    for (int c = t; c < KPADC; c += 256) {
        float v = (c < F_CELL) ? cell[(size_t)b * F_CELL + c] * inv : 0.f;
        celln[(size_t)b * KPADC + c] = f2bf(v);
    }
}

__global__ void final_out(const float* __restrict__ xg, const float* __restrict__ xc3,
                          const float* __restrict__ Wo, const float* __restrict__ bo,
                          float* __restrict__ out)
{
    int b = blockIdx.x, t = threadIdx.x;   // 128 threads
    float v = xc3[b * HID + t];
    float p0 = v * Wo[t * 2], p1 = v * Wo[t * 2 + 1];
    __shared__ float s[4];
#pragma unroll
    for (int o = 32; o > 0; o >>= 1) { p0 += __shfl_down(p0, o); p1 += __shfl_down(p1, o); }
    if ((t & 63) == 0) { s[(t >> 6) * 2] = p0; s[(t >> 6) * 2 + 1] = p1; }
    __syncthreads();
    out[b * 130 + t] = xg[b * HID + t];
    if (t == 0) {
        out[b * 130 + 128] = s[0] + s[2] + bo[0];
        out[b * 130 + 129] = s[1] + s[3] + bo[1];
    }
}

extern "C" void kernel_launch(void* const* d_in, const int* in_sizes, int n_in,
                              void* d_out, int out_size, void* d_ws, size_t ws_size,
                              hipStream_t stream)
{
    const float* x    = (const float*)d_in[0];
    const int*   ei   = (const int*)d_in[1];
    const int*   batch= (const int*)d_in[2];
    const float* cell = (const float*)d_in[3];
    const float* W1   = (const float*)d_in[4];
    const float* as1  = (const float*)d_in[5];
    const float* ad1  = (const float*)d_in[6];
    const float* b1   = (const float*)d_in[7];
    const float* W2   = (const float*)d_in[8];
    const float* as2  = (const float*)d_in[9];
    const float* ad2  = (const float*)d_in[10];
    const float* b2   = (const float*)d_in[11];
    const float* Wg   = (const float*)d_in[12];
    const float* bg   = (const float*)d_in[13];
    const float* Wf1  = (const float*)d_in[14];
    const float* bf1  = (const float*)d_in[15];
    const float* Wf2  = (const float*)d_in[16];
    const float* bf2  = (const float*)d_in[17];
    const float* Wf3  = (const float*)d_in[18];
    const float* bf3  = (const float*)d_in[19];
    const float* Wo   = (const float*)d_in[20];
    const float* bo   = (const float*)d_in[21];
    float* out = (float*)d_out;

    char* w = (char*)d_ws;
    auto alloc = [&](size_t bytes) { char* p = w; w += (bytes + 255) & ~(size_t)255; return p; };
    unsigned short* xb   = (unsigned short*)alloc((size_t)N_NODES * KPAD1 * 2);
    unsigned short* W1T  = (unsigned short*)alloc((size_t)NPAD1 * KPAD1 * 2);
    unsigned short* H1   = (unsigned short*)alloc((size_t)N_NODES * NPAD1 * 2);   // 46 MB
    unsigned short* x1   = (unsigned short*)alloc((size_t)N_NODES * F1 * 2);      // 42 MB
    unsigned short* W2T  = (unsigned short*)alloc((size_t)NPAD2 * F1 * 2);
    unsigned short* H2   = (unsigned short*)alloc((size_t)N_NODES * NPAD2 * 2);   // 5.2 MB
    float*    x2   = (float*)alloc((size_t)N_NODES * HID * 4);
    int*      counts    = (int*)alloc((size_t)N_NODES * 4);
    int*      row_start = (int*)alloc((size_t)(N_NODES + 1) * 4);
    int*      cursor    = (int*)alloc((size_t)N_NODES * 4);
    int*      csr_src   = (int*)alloc((size_t)ETOT * 4);
    unsigned* pk   = (unsigned*)alloc((size_t)BGRAPH * HID * 4);
    unsigned short* pooledb = (unsigned short*)alloc((size_t)BGRAPH * HID * 2);
    unsigned short* WgT  = (unsigned short*)alloc((size_t)HID * HID * 2);
    float*    xg   = (float*)alloc((size_t)BGRAPH * HID * 4);
    unsigned short* celln = (unsigned short*)alloc((size_t)BGRAPH * KPADC * 2);
    unsigned short* Wf1T = (unsigned short*)alloc((size_t)2048 * KPADC * 2);
    unsigned short* Wf2T = (unsigned short*)alloc((size_t)512 * 2048 * 2);
    unsigned short* Wf3T = (unsigned short*)alloc((size_t)HID * 512 * 2);
    unsigned short* xc1b = (unsigned short*)alloc((size_t)BGRAPH * 2048 * 2);
    unsigned short* xc2b = (unsigned short*)alloc((size_t)BGRAPH * 512 * 2);
    float*    xc3  = (float*)alloc((size_t)BGRAPH * HID * 4);

    hipMemsetAsync(counts, 0, (size_t)N_NODES * 4, stream);
    hipMemsetAsync(pk,     0, (size_t)BGRAPH * HID * 4, stream);

    dim3 b256(256);
    const int egrid = (ETOT + 255) / 256;

    // ---- weight prep (1 mega-kernel + 2 small folds) ----
    prep_weights<<<PREP_TOTAL / 256, b256, 0, stream>>>(x, W1, W2, Wf1, Wf2, Wf3, Wg,
                                                        xb, W1T, W2T, Wf1T, Wf2T, Wf3T, WgT);
    fold_a1<<<2 * HEADS, 64, 0, stream>>>(W1, as1, ad1, W1T);
    fold_a2<<<(2 * F1 + 255) / 256, b256, 0, stream>>>(W2, as2, ad2, W2T);

    // ---- CSR build ----
    hist_dst<<<egrid, b256, 0, stream>>>(ei, counts);
    scan_counts<<<1, b256, 0, stream>>>(counts, row_start, cursor);
    scatter_csr<<<egrid, b256, 0, stream>>>(ei, cursor, csr_src);

    // ---- GAT layer 1: H1' = x @ [W1 | es | ed] ----
    mfma_gemm<4, 4, 1, 0, 0><<<dim3(NPAD1 / 128, N_NODES / 128), b256, 0, stream>>>(
        xb, W1T, nullptr, H1, N_NODES, NPAD1, KPAD1);
    gat1_agg<<<N_NODES / 4, b256, 0, stream>>>(row_start, csr_src, H1, b1, x1);

    // ---- GAT layer 2: H2' = x1 @ [W2 | es2 | ed2] (BN=160 in one block-col) ----
    mfma_gemm<2, 5, 1, 0, 0><<<dim3(1, N_NODES / 64), b256, 0, stream>>>(
        x1, W2T, nullptr, H2, N_NODES, NPAD2, F1);
    gat2_agg<<<N_NODES / 4, b256, 0, stream>>>(row_start, csr_src, H2, b2, x2);

    // ---- pool + drug fc ----
    pool_max<<<(N_NODES * HID + 255) / 256, b256, 0, stream>>>(x2, batch, pk);
    decode_keys_bf16<<<(BGRAPH * HID + 255) / 256, b256, 0, stream>>>(pk, pooledb, BGRAPH * HID);
    mfma_gemm<2, 2, 0, 1, 1><<<dim3(HID / 64, BGRAPH / 64), b256, 0, stream>>>(
        pooledb, WgT, bg, xg, BGRAPH, HID, HID);

    // ---- cell branch (fused bias+relu epilogues) ----
    cell_norm<<<BGRAPH, b256, 0, stream>>>(cell, celln);
    mfma_gemm<2, 2, 1, 1, 1><<<dim3(2048 / 64, BGRAPH / 64), b256, 0, stream>>>(
        celln, Wf1T, bf1, xc1b, BGRAPH, 2048, KPADC);
    mfma_gemm<1, 2, 1, 1, 1><<<dim3(512 / 64, BGRAPH / 32), b256, 0, stream>>>(
        xc1b, Wf2T, bf2, xc2b, BGRAPH, 512, 2048);
    mfma_gemm<2, 2, 0, 1, 1><<<dim3(HID / 64, BGRAPH / 64), b256, 0, stream>>>(
        xc2b, Wf3T, bf3, xc3, BGRAPH, HID, 512);

    // ---- output head + concat ----
    final_out<<<BGRAPH, 128, 0, stream>>>(xg, xc3, Wo, bo, out);
}

// Round 6
// 289.588 us; speedup vs baseline: 1.1769x; 1.1769x over previous
//
#include <hip/hip_runtime.h>
#include <hip/hip_bf16.h>
#include <math.h>

#define N_NODES 16384
#define E_EDGES 131072
#define ETOT (E_EDGES + N_NODES)   // 147456 (self-loops appended)
#define BGRAPH 256
#define F_INPUT 78
#define KPAD1 96                   // F_INPUT padded to mult of 32
#define HID 128
#define HEADS 10
#define F1 (HEADS * HID)           // 1280
#define F_CELL 954
#define KPADC 960                  // F_CELL padded
#define NEG_SLOPE 0.2f

typedef __attribute__((ext_vector_type(8))) short frag_t;   // 8 bf16
typedef __attribute__((ext_vector_type(4))) float f4_t;
typedef __attribute__((ext_vector_type(8))) unsigned short u16x8;

static __device__ __forceinline__ unsigned fkey(float f) {
    unsigned b = __float_as_uint(f);
    return (b & 0x80000000u) ? ~b : (b | 0x80000000u);
}
static __device__ __forceinline__ float funkey(unsigned k) {
    unsigned b = (k & 0x80000000u) ? (k ^ 0x80000000u) : ~k;
    return __uint_as_float(b);
}
static __device__ __forceinline__ unsigned short f2bf(float f) {
    __hip_bfloat16 h = __float2bfloat16(f);
    return *(unsigned short*)&h;
}
static __device__ __forceinline__ float bf2f(unsigned short u) {
    return __uint_as_float(((unsigned)u) << 16);
}

// ================= MFMA bf16 GEMM =================
// A [M,Kpad] bf16, BT [N,Kpad] bf16. C row-major [M,N].
// OUT_MODE: 0 = f32, 1 = bf16, 2 = coef (cols 0..9 -> es[row*10+c], 16..25 -> ed).
template<int WM16, int WN16, int OUT_MODE, int ACT, int HAS_BIAS>
__global__ __launch_bounds__(256) void mfma_gemm(
    const unsigned short* __restrict__ A, const unsigned short* __restrict__ BT,
    const float* __restrict__ bias, void* __restrict__ C,
    float* __restrict__ esp, float* __restrict__ edp,
    int M, int N, int Kpad)
{
    constexpr int BM = 32 * WM16, BN = 32 * WN16;
    __shared__ __align__(16) unsigned short Als[BM * 32];
    __shared__ __align__(16) unsigned short Bls[BN * 32];
    const int t = threadIdx.x;
    const int wave = t >> 6, lane = t & 63;
    const int wr = (wave >> 1) * (16 * WM16);
    const int wc = (wave & 1) * (16 * WN16);
    const int row0 = blockIdx.y * BM;
    const int col0 = blockIdx.x * BN;

    f4_t acc[WM16][WN16];
#pragma unroll
    for (int m = 0; m < WM16; m++)
#pragma unroll
        for (int n = 0; n < WN16; n++) { acc[m][n] = (f4_t){0.f, 0.f, 0.f, 0.f}; }

    const int lrow = lane & 15, kg = lane >> 4;
    for (int kk = 0; kk < Kpad; kk += 32) {
        for (int i = t; i < BM * 4; i += 256) {
            int r = i >> 2, slot = i & 3;
            uint4 v = *(const uint4*)&A[(size_t)(row0 + r) * Kpad + kk + slot * 8];
            *(uint4*)&Als[r * 32 + ((slot ^ (r & 3) ^ ((r >> 2) & 3)) * 8)] = v;
        }
        for (int i = t; i < BN * 4; i += 256) {
            int r = i >> 2, slot = i & 3;
            uint4 v = *(const uint4*)&BT[(size_t)(col0 + r) * Kpad + kk + slot * 8];
            *(uint4*)&Bls[r * 32 + ((slot ^ (r & 3) ^ ((r >> 2) & 3)) * 8)] = v;
        }
        __syncthreads();
        frag_t af[WM16], bfr[WN16];
#pragma unroll
        for (int m = 0; m < WM16; m++) {
            int r = wr + m * 16 + lrow;
            af[m] = *(frag_t*)&Als[r * 32 + ((kg ^ (r & 3) ^ ((r >> 2) & 3)) * 8)];
        }
#pragma unroll
        for (int n = 0; n < WN16; n++) {
            int r = wc + n * 16 + lrow;
            bfr[n] = *(frag_t*)&Bls[r * 32 + ((kg ^ (r & 3) ^ ((r >> 2) & 3)) * 8)];
        }
#pragma unroll
        for (int m = 0; m < WM16; m++)
#pragma unroll
            for (int n = 0; n < WN16; n++)
                acc[m][n] = __builtin_amdgcn_mfma_f32_16x16x32_bf16(af[m], bfr[n], acc[m][n], 0, 0, 0);
        __syncthreads();
    }

#pragma unroll
    for (int m = 0; m < WM16; m++) {
#pragma unroll
        for (int n = 0; n < WN16; n++) {
            int col = col0 + wc + n * 16 + lrow;
            float bv = HAS_BIAS ? bias[col] : 0.f;
#pragma unroll
            for (int r = 0; r < 4; r++) {
                int row = row0 + wr + m * 16 + kg * 4 + r;
                float v = acc[m][n][r] + bv;
                if (ACT) v = fmaxf(v, 0.f);
                if (OUT_MODE == 0)      ((float*)C)[(size_t)row * N + col] = v;
                else if (OUT_MODE == 1) ((unsigned short*)C)[(size_t)row * N + col] = f2bf(v);
                else {
                    if (col < 10)                  esp[row * 10 + col] = v;
                    else if (col >= 16 && col < 26) edp[row * 10 + (col - 16)] = v;
                }
            }
        }
    }
}

// ================= mega weight-prep =================
#define S0 1572864   // xb: 16384*96
#define S1 122880    // W1T: 1280*96
#define S2 163840    // W2T: 128*1280
#define S3 1966080   // Wf1T: 2048*960
#define S4 1048576   // Wf2T: 512*2048
#define S5 65536     // Wf3T: 128*512
#define S6 16384     // WgT: 128*128
#define PREP_TOTAL (S0+S1+S2+S3+S4+S5+S6)   // 4956160 = 19360*256

__global__ void prep_weights(const float* __restrict__ x,  const float* __restrict__ W1,
                             const float* __restrict__ W2, const float* __restrict__ Wf1,
                             const float* __restrict__ Wf2, const float* __restrict__ Wf3,
                             const float* __restrict__ Wg,
                             unsigned short* __restrict__ xb,  unsigned short* __restrict__ W1T,
                             unsigned short* __restrict__ W2T, unsigned short* __restrict__ Wf1T,
                             unsigned short* __restrict__ Wf2T, unsigned short* __restrict__ Wf3T,
                             unsigned short* __restrict__ WgT)
{
    int i = blockIdx.x * 256 + threadIdx.x;
    if (i < S0) { int r = i / 96, k = i % 96;
        xb[i] = (k < F_INPUT) ? f2bf(x[r * F_INPUT + k]) : 0; return; }
    i -= S0;
    if (i < S1) { int n = i / 96, k = i % 96;
        W1T[i] = (k < F_INPUT) ? f2bf(W1[(size_t)k * F1 + n]) : 0; return; }
    i -= S1;
    if (i < S2) { int n = i / 1280, k = i % 1280;
        W2T[i] = f2bf(W2[(size_t)k * HID + n]); return; }
    i -= S2;
    if (i < S3) { int n = i / 960, k = i % 960;
        Wf1T[i] = (k < F_CELL) ? f2bf(Wf1[(size_t)k * 2048 + n]) : 0; return; }
    i -= S3;
    if (i < S4) { int n = i / 2048, k = i % 2048;
        Wf2T[i] = f2bf(Wf2[(size_t)k * 512 + n]); return; }
    i -= S4;
    if (i < S5) { int n = i / 512, k = i % 512;
        Wf3T[i] = f2bf(Wf3[(size_t)k * HID + n]); return; }
    i -= S5;
    { int n = i / 128, k = i % 128;
        WgT[i] = f2bf(Wg[(size_t)k * HID + n]); }
}

// F1T [32,96] bf16: row r = sd*16+h holds fold of W1 with a_{s|d}[h]; wave per entry.
__global__ void fold1_w(const float* __restrict__ W1, const float* __restrict__ as_,
                        const float* __restrict__ ad_, unsigned short* __restrict__ F1T)
{
    int idx = blockIdx.x * 4 + (threadIdx.x >> 6);   // 0..3071
    int l = threadIdx.x & 63;
    int r = idx / 96, k = idx % 96;
    int sd = r >> 4, h = r & 15;
    float p = 0.f;
    if (h < HEADS && k < F_INPUT) {
        const float* a = (sd ? ad_ : as_) + h * HID;
        float2 wv = *(const float2*)&W1[(size_t)k * F1 + h * HID + 2 * l];
        float2 av = *(const float2*)&a[2 * l];
        p = wv.x * av.x + wv.y * av.y;
#pragma unroll
        for (int o = 32; o > 0; o >>= 1) p += __shfl_xor(p, o);
    }
    if (l == 0) F1T[(size_t)r * 96 + k] = f2bf(p);
}

// ================= CSR build (by dst) =================
__global__ void hist_dst(const int* __restrict__ ei, int* __restrict__ counts)
{
    int e = blockIdx.x * blockDim.x + threadIdx.x;
    if (e >= ETOT) return;
    int dst = (e < E_EDGES) ? ei[E_EDGES + e] : (e - E_EDGES);
    atomicAdd(&counts[dst], 1);
}

__global__ void scan_counts(const int* __restrict__ counts,
                            int* __restrict__ row_start, int* __restrict__ cursor)
{
    __shared__ int part[256];
    int t = threadIdx.x;
    int base = t * 64;
    int sum = 0;
    for (int i = 0; i < 64; i++) sum += counts[base + i];
    part[t] = sum;
    __syncthreads();
    for (int o = 1; o < 256; o <<= 1) {
        int v = 0;
        if (t >= o) v = part[t - o];
        __syncthreads();
        part[t] += v;
        __syncthreads();
    }
    int run = (t == 0) ? 0 : part[t - 1];
    for (int i = 0; i < 64; i++) {
        row_start[base + i] = run;
        cursor[base + i] = run;
        run += counts[base + i];
    }
    if (t == 255) row_start[N_NODES] = run;
}

__global__ void scatter_csr(const int* __restrict__ ei, int* __restrict__ cursor,
                            int* __restrict__ csr_src)
{
    int e = blockIdx.x * blockDim.x + threadIdx.x;
    if (e >= ETOT) return;
    int src, dst;
    if (e < E_EDGES) { src = ei[e]; dst = ei[E_EDGES + e]; } else { src = dst = e - E_EDGES; }
    int pos = atomicAdd(&cursor[dst], 1);
    csr_src[pos] = src;
}

// ================= layer-2 attention coefficients (wave per node, bf16 H2) =====
__global__ void attn_coef2(const unsigned short* __restrict__ H2,
                           const float* __restrict__ as_, const float* __restrict__ ad_,
                           float* __restrict__ es, float* __restrict__ ed)
{
    int n = blockIdx.x * 4 + (threadIdx.x >> 6);
    int l = threadIdx.x & 63;
    unsigned p = *(const unsigned*)&H2[(size_t)n * HID + 2 * l];
    float h0 = bf2f((unsigned short)(p & 0xffffu));
    float h1 = bf2f((unsigned short)(p >> 16));
    float2 av = *(const float2*)&as_[2 * l];
    float2 dv = *(const float2*)&ad_[2 * l];
    float vs = h0 * av.x + h1 * av.y;
    float vd = h0 * dv.x + h1 * dv.y;
#pragma unroll
    for (int o = 32; o > 0; o >>= 1) { vs += __shfl_xor(vs, o); vd += __shfl_xor(vd, o); }
    if (l == 0) { es[n] = vs; ed[n] = vd; }
}

// ================= GAT layer-1 aggregation: WAVE per dst node (R4-proven) ======
__global__ __launch_bounds__(256) void gat1_agg(
    const int* __restrict__ row_start, const int* __restrict__ csr_src,
    const unsigned short* __restrict__ H,
    const float* __restrict__ es, const float* __restrict__ ed,
    const float* __restrict__ b, unsigned short* __restrict__ xout)
{
    const int w = threadIdx.x >> 6, l = threadIdx.x & 63;
    const int n = blockIdx.x * 4 + w;
    const int rs = row_start[n];
    const int deg = row_start[n + 1] - rs;
    const int hi = l >> 4;

    __shared__ float w_lds[4][64][11];
    __shared__ int   src_lds[4][64];

    float edv[HEADS];
    const float* edp = ed + n * HEADS;
#pragma unroll
    for (int h = 0; h < HEADS; h++) edv[h] = edp[h];

    // ---- pass A: per-head max (lanes = edges) ----
    float m[HEADS];
#pragma unroll
    for (int h = 0; h < HEADS; h++) m[h] = -INFINITY;
    for (int base = 0; base < deg; base += 64) {
        int e = base + l;
        if (e < deg) {
            int s = csr_src[rs + e];
            const float* ep = es + s * HEADS;
#pragma unroll
            for (int h = 0; h < HEADS; h++) {
                float v = ep[h] + edv[h];
                v = (v >= 0.f) ? v : NEG_SLOPE * v;
                m[h] = fmaxf(m[h], v);
            }
        }
    }
#pragma unroll
    for (int h = 0; h < HEADS; h++)
#pragma unroll
        for (int o = 32; o > 0; o >>= 1) m[h] = fmaxf(m[h], __shfl_xor(m[h], o));

    // ---- pass B: weights + channel-parallel accumulation ----
    float acc[3][8];
#pragma unroll
    for (int s0 = 0; s0 < 3; s0++)
#pragma unroll
        for (int k = 0; k < 8; k++) acc[s0][k] = 0.f;
    float den[HEADS];
#pragma unroll
    for (int h = 0; h < HEADS; h++) den[h] = 0.f;

    for (int base = 0; base < deg; base += 64) {
        int e = base + l;
        int cnt = min(64, deg - base);
        float wv[HEADS];
        if (e < deg) {
            int s = csr_src[rs + e];
            src_lds[w][l] = s;
            const float* ep = es + s * HEADS;
#pragma unroll
            for (int h = 0; h < HEADS; h++) {
                float v = ep[h] + edv[h];
                v = (v >= 0.f) ? v : NEG_SLOPE * v;
                wv[h] = __expf(v - m[h]);
            }
        } else {
#pragma unroll
            for (int h = 0; h < HEADS; h++) wv[h] = 0.f;
        }
#pragma unroll
        for (int h = 0; h < HEADS; h++) {
            den[h] += wv[h];
            w_lds[w][l][h] = wv[h];
        }
        asm volatile("" ::: "memory");

        for (int j = 0; j < cnt; j++) {
            int sj = src_lds[w][j];
            const unsigned short* hrow = H + (size_t)sj * F1;
#pragma unroll
            for (int slot = 0; slot < 3; slot++) {
                if (slot < 2 || l < 32) {
                    int c0 = slot * 512 + l * 8;
                    float wj = w_lds[w][j][slot * 4 + hi];
                    u16x8 v = *(const u16x8*)&hrow[c0];
#pragma unroll
                    for (int k = 0; k < 8; k++)
                        acc[slot][k] = fmaf(wj, bf2f((unsigned short)v[k]), acc[slot][k]);
                }
            }
        }
        asm volatile("" ::: "memory");
    }

#pragma unroll
    for (int h = 0; h < HEADS; h++)
#pragma unroll
        for (int o = 32; o > 0; o >>= 1) den[h] += __shfl_xor(den[h], o);

    unsigned short* orow = xout + (size_t)n * F1;
#pragma unroll
    for (int slot = 0; slot < 3; slot++) {
        if (slot < 2 || l < 32) {
            int c0 = slot * 512 + l * 8;
            float dh;
            if (slot == 2) dh = (hi & 1) ? den[9] : den[8];
            else dh = (hi == 0) ? den[slot * 4] : (hi == 1) ? den[slot * 4 + 1]
                    : (hi == 2) ? den[slot * 4 + 2] : den[slot * 4 + 3];
            float inv = 1.f / dh;
            float4 b0 = *(const float4*)&b[c0];
            float4 b1 = *(const float4*)&b[c0 + 4];
            float bb[8] = {b0.x, b0.y, b0.z, b0.w, b1.x, b1.y, b1.z, b1.w};
            u16x8 ov;
#pragma unroll
            for (int k = 0; k < 8; k++) {
                float v = acc[slot][k] * inv + bb[k];
                ov[k] = f2bf((v > 0.f) ? v : expm1f(v));
            }
            *(u16x8*)&orow[c0] = ov;
        }
    }
}

// ================= GAT layer-2 aggregation: WAVE per dst (bf16 H2) =============
__global__ __launch_bounds__(256) void gat2_agg(
    const int* __restrict__ row_start, const int* __restrict__ csr_src,
    const unsigned short* __restrict__ H2,
    const float* __restrict__ es, const float* __restrict__ ed,
    const float* __restrict__ b, float* __restrict__ xout)
{
    const int w = threadIdx.x >> 6, l = threadIdx.x & 63;
    const int n = blockIdx.x * 4 + w;
    const int rs = row_start[n];
    const int deg = row_start[n + 1] - rs;
    const float edv = ed[n];

    float m = -INFINITY;
    for (int base = 0; base < deg; base += 64) {
        int e = base + l;
        if (e < deg) {
            int s = csr_src[rs + e];
            float v = es[s] + edv;
            v = (v >= 0.f) ? v : NEG_SLOPE * v;
            m = fmaxf(m, v);
        }
    }
#pragma unroll
    for (int o = 32; o > 0; o >>= 1) m = fmaxf(m, __shfl_xor(m, o));

    float2 acc = {0.f, 0.f};
    float den = 0.f;
    for (int base = 0; base < deg; base += 64) {
        int e = base + l;
        int cnt = min(64, deg - base);
        int s = 0;
        float wv = 0.f;
        if (e < deg) {
            s = csr_src[rs + e];
            float v = es[s] + edv;
            v = (v >= 0.f) ? v : NEG_SLOPE * v;
            wv = __expf(v - m);
        }
        den += wv;
        for (int j = 0; j < cnt; j++) {
            float wj = __shfl(wv, j);
            int   sj = __shfl(s, j);
            unsigned hp = *(const unsigned*)&H2[(size_t)sj * HID + 2 * l];
            acc.x = fmaf(wj, bf2f((unsigned short)(hp & 0xffffu)), acc.x);
            acc.y = fmaf(wj, bf2f((unsigned short)(hp >> 16)), acc.y);
        }
    }
#pragma unroll
    for (int o = 32; o > 0; o >>= 1) den += __shfl_xor(den, o);

    float inv = 1.f / den;
    float2 bv = *(const float2*)&b[2 * l];
    float v0 = acc.x * inv + bv.x;
    float v1 = acc.y * inv + bv.y;
    float2 ov;
    ov.x = (v0 > 0.f) ? v0 : expm1f(v0);
    ov.y = (v1 > 0.f) ? v1 : expm1f(v1);
    *(float2*)(xout + (size_t)n * HID + 2 * l) = ov;
}

// ================= pool / cell / final =================
__global__ void pool_max(const float* __restrict__ x2, const int* __restrict__ batch,
                         unsigned* __restrict__ pk)
{
    int idx = blockIdx.x * blockDim.x + threadIdx.x;
    if (idx >= N_NODES * HID) return;
    int n = idx >> 7, c = idx & 127;
    atomicMax(&pk[batch[n] * HID + c], fkey(x2[idx]));
}

__global__ void decode_keys_bf16(const unsigned* __restrict__ pk,
                                 unsigned short* __restrict__ outb, int count)
{
    int i = blockIdx.x * blockDim.x + threadIdx.x;
    if (i < count) outb[i] = f2bf(funkey(pk[i]));
}

__global__ void cell_norm(const float* __restrict__ cell, unsigned short* __restrict__ celln)
{
    int b = blockIdx.x;     // 256 rows
    int t = threadIdx.x;    // 256 threads
    __shared__ float red[256];
    float s = 0.f;
    for (int c = t; c < F_CELL; c += 256) { float v = cell[(size_t)b * F_CELL + c]; s += v * v; }
    red[t] = s; __syncthreads();
    for (int o = 128; o > 0; o >>= 1) { if (t < o) red[t] += red[t + o]; __syncthreads(); }
    float inv = 1.f / fmaxf(sqrtf(red[0]), 1e-12f);
    for (int c = t; c < KPADC; c += 256) {
        float v = (c < F_CELL) ? cell[(size_t)b * F_CELL + c] * inv : 0.f;
        celln[(size_t)b * KPADC + c] = f2bf(v);
    }
}

__global__ void final_out(const float* __restrict__ xg, const float* __restrict__ xc3,
                          const float* __restrict__ Wo, const float* __restrict__ bo,
                          float* __restrict__ out)
{
    int b = blockIdx.x, t = threadIdx.x;   // 128 threads
    float v = xc3[b * HID + t];
    float p0 = v * Wo[t * 2], p1 = v * Wo[t * 2 + 1];
    __shared__ float s[4];
#pragma unroll
    for (int o = 32; o > 0; o >>= 1) { p0 += __shfl_down(p0, o); p1 += __shfl_down(p1, o); }
    if ((t & 63) == 0) { s[(t >> 6) * 2] = p0; s[(t >> 6) * 2 + 1] = p1; }
    __syncthreads();
    out[b * 130 + t] = xg[b * HID + t];
    if (t == 0) {
        out[b * 130 + 128] = s[0] + s[2] + bo[0];
        out[b * 130 + 129] = s[1] + s[3] + bo[1];
    }
}

extern "C" void kernel_launch(void* const* d_in, const int* in_sizes, int n_in,
                              void* d_out, int out_size, void* d_ws, size_t ws_size,
                              hipStream_t stream)
{
    const float* x    = (const float*)d_in[0];
    const int*   ei   = (const int*)d_in[1];
    const int*   batch= (const int*)d_in[2];
    const float* cell = (const float*)d_in[3];
    const float* W1   = (const float*)d_in[4];
    const float* as1  = (const float*)d_in[5];
    const float* ad1  = (const float*)d_in[6];
    const float* b1   = (const float*)d_in[7];
    const float* W2   = (const float*)d_in[8];
    const float* as2  = (const float*)d_in[9];
    const float* ad2  = (const float*)d_in[10];
    const float* b2   = (const float*)d_in[11];
    const float* Wg   = (const float*)d_in[12];
    const float* bg   = (const float*)d_in[13];
    const float* Wf1  = (const float*)d_in[14];
    const float* bf1  = (const float*)d_in[15];
    const float* Wf2  = (const float*)d_in[16];
    const float* bf2  = (const float*)d_in[17];
    const float* Wf3  = (const float*)d_in[18];
    const float* bf3  = (const float*)d_in[19];
    const float* Wo   = (const float*)d_in[20];
    const float* bo   = (const float*)d_in[21];
    float* out = (float*)d_out;

    char* w = (char*)d_ws;
    auto alloc = [&](size_t bytes) { char* p = w; w += (bytes + 255) & ~(size_t)255; return p; };
    unsigned short* xb   = (unsigned short*)alloc((size_t)N_NODES * KPAD1 * 2);
    unsigned short* W1T  = (unsigned short*)alloc((size_t)F1 * KPAD1 * 2);
    unsigned short* F1T  = (unsigned short*)alloc((size_t)32 * KPAD1 * 2);
    unsigned short* H1   = (unsigned short*)alloc((size_t)N_NODES * F1 * 2);      // 42 MB
    unsigned short* x1   = (unsigned short*)alloc((size_t)N_NODES * F1 * 2);      // 42 MB
    unsigned short* W2T  = (unsigned short*)alloc((size_t)HID * F1 * 2);
    unsigned short* H2   = (unsigned short*)alloc((size_t)N_NODES * HID * 2);     // 4.2 MB
    float*    es1  = (float*)alloc((size_t)N_NODES * HEADS * 4);
    float*    ed1  = (float*)alloc((size_t)N_NODES * HEADS * 4);
    float*    es2  = (float*)alloc((size_t)N_NODES * 4);
    float*    ed2  = (float*)alloc((size_t)N_NODES * 4);
    float*    x2   = (float*)alloc((size_t)N_NODES * HID * 4);
    int*      counts    = (int*)alloc((size_t)N_NODES * 4);
    int*      row_start = (int*)alloc((size_t)(N_NODES + 1) * 4);
    int*      cursor    = (int*)alloc((size_t)N_NODES * 4);
    int*      csr_src   = (int*)alloc((size_t)ETOT * 4);
    unsigned* pk   = (unsigned*)alloc((size_t)BGRAPH * HID * 4);
    unsigned short* pooledb = (unsigned short*)alloc((size_t)BGRAPH * HID * 2);
    unsigned short* WgT  = (unsigned short*)alloc((size_t)HID * HID * 2);
    float*    xg   = (float*)alloc((size_t)BGRAPH * HID * 4);
    unsigned short* celln = (unsigned short*)alloc((size_t)BGRAPH * KPADC * 2);
    unsigned short* Wf1T = (unsigned short*)alloc((size_t)2048 * KPADC * 2);
    unsigned short* Wf2T = (unsigned short*)alloc((size_t)512 * 2048 * 2);
    unsigned short* Wf3T = (unsigned short*)alloc((size_t)HID * 512 * 2);
    unsigned short* xc1b = (unsigned short*)alloc((size_t)BGRAPH * 2048 * 2);
    unsigned short* xc2b = (unsigned short*)alloc((size_t)BGRAPH * 512 * 2);
    float*    xc3  = (float*)alloc((size_t)BGRAPH * HID * 4);

    hipMemsetAsync(counts, 0, (size_t)N_NODES * 4, stream);
    hipMemsetAsync(pk,     0, (size_t)BGRAPH * HID * 4, stream);

    dim3 b256(256);
    const int egrid = (ETOT + 255) / 256;

    // ---- weight prep ----
    prep_weights<<<PREP_TOTAL / 256, b256, 0, stream>>>(x, W1, W2, Wf1, Wf2, Wf3, Wg,
                                                        xb, W1T, W2T, Wf1T, Wf2T, Wf3T, WgT);
    fold1_w<<<32 * 96 / 4, b256, 0, stream>>>(W1, as1, ad1, F1T);

    // ---- CSR build ----
    hist_dst<<<egrid, b256, 0, stream>>>(ei, counts);
    scan_counts<<<1, b256, 0, stream>>>(counts, row_start, cursor);
    scatter_csr<<<egrid, b256, 0, stream>>>(ei, cursor, csr_src);

    // ---- GAT layer 1 ----
    mfma_gemm<4, 4, 1, 0, 0><<<dim3(F1 / 128, N_NODES / 128), b256, 0, stream>>>(
        xb, W1T, nullptr, H1, nullptr, nullptr, N_NODES, F1, KPAD1);
    mfma_gemm<4, 1, 2, 0, 0><<<dim3(1, N_NODES / 128), b256, 0, stream>>>(
        xb, F1T, nullptr, nullptr, es1, ed1, N_NODES, 32, KPAD1);
    gat1_agg<<<N_NODES / 4, b256, 0, stream>>>(row_start, csr_src, H1, es1, ed1, b1, x1);

    // ---- GAT layer 2 ----
    mfma_gemm<2, 4, 1, 0, 0><<<dim3(1, N_NODES / 64), b256, 0, stream>>>(
        x1, W2T, nullptr, H2, nullptr, nullptr, N_NODES, HID, F1);
    attn_coef2<<<N_NODES / 4, b256, 0, stream>>>(H2, as2, ad2, es2, ed2);
    gat2_agg<<<N_NODES / 4, b256, 0, stream>>>(row_start, csr_src, H2, es2, ed2, b2, x2);

    // ---- pool + drug fc ----
    pool_max<<<(N_NODES * HID + 255) / 256, b256, 0, stream>>>(x2, batch, pk);
    decode_keys_bf16<<<(BGRAPH * HID + 255) / 256, b256, 0, stream>>>(pk, pooledb, BGRAPH * HID);
    mfma_gemm<2, 2, 0, 1, 1><<<dim3(HID / 64, BGRAPH / 64), b256, 0, stream>>>(
        pooledb, WgT, bg, xg, nullptr, nullptr, BGRAPH, HID, HID);

    // ---- cell branch ----
    cell_norm<<<BGRAPH, b256, 0, stream>>>(cell, celln);
    mfma_gemm<2, 2, 1, 1, 1><<<dim3(2048 / 64, BGRAPH / 64), b256, 0, stream>>>(
        celln, Wf1T, bf1, xc1b, nullptr, nullptr, BGRAPH, 2048, KPADC);
    mfma_gemm<1, 2, 1, 1, 1><<<dim3(512 / 64, BGRAPH / 32), b256, 0, stream>>>(
        xc1b, Wf2T, bf2, xc2b, nullptr, nullptr, BGRAPH, 512, 2048);
    mfma_gemm<2, 2, 0, 1, 1><<<dim3(HID / 64, BGRAPH / 64), b256, 0, stream>>>(
        xc2b, Wf3T, bf3, xc3, nullptr, nullptr, BGRAPH, HID, 512);

    // ---- output head + concat ----
    final_out<<<BGRAPH, 128, 0, stream>>>(xg, xc3, Wo, bo, out);
}

// Round 7
// 282.364 us; speedup vs baseline: 1.2071x; 1.0256x over previous
//
#include <hip/hip_runtime.h>
#include <hip/hip_bf16.h>
#include <math.h>

#define N_NODES 16384
#define E_EDGES 131072
#define ETOT (E_EDGES + N_NODES)   // 147456 (self-loops appended)
#define BGRAPH 256
#define F_INPUT 78
#define KPAD1 96                   // F_INPUT padded to mult of 32
#define HID 128
#define HEADS 10
#define F1 (HEADS * HID)           // 1280
#define F_CELL 954
#define KPADC 960                  // F_CELL padded
#define NEG_SLOPE 0.2f

typedef __attribute__((ext_vector_type(8))) short frag_t;   // 8 bf16
typedef __attribute__((ext_vector_type(4))) float f4_t;
typedef __attribute__((ext_vector_type(8))) unsigned short u16x8;

static __device__ __forceinline__ unsigned fkey(float f) {
    unsigned b = __float_as_uint(f);
    return (b & 0x80000000u) ? ~b : (b | 0x80000000u);
}
static __device__ __forceinline__ float funkey(unsigned k) {
    unsigned b = (k & 0x80000000u) ? (k ^ 0x80000000u) : ~k;
    return __uint_as_float(b);
}
static __device__ __forceinline__ unsigned short f2bf(float f) {
    __hip_bfloat16 h = __float2bfloat16(f);
    return *(unsigned short*)&h;
}
static __device__ __forceinline__ float bf2f(unsigned short u) {
    return __uint_as_float(((unsigned)u) << 16);
}

// ================= MFMA bf16 GEMM =================
// A [M,Kpad] bf16, BT [N,Kpad] bf16. C row-major [M,N].
// OUT_MODE: 0 = f32, 1 = bf16, 2 = coef (cols 0..9 -> es[row*10+c], 16..25 -> ed).
template<int WM16, int WN16, int OUT_MODE, int ACT, int HAS_BIAS>
__global__ __launch_bounds__(256) void mfma_gemm(
    const unsigned short* __restrict__ A, const unsigned short* __restrict__ BT,
    const float* __restrict__ bias, void* __restrict__ C,
    float* __restrict__ esp, float* __restrict__ edp,
    int M, int N, int Kpad)
{
    constexpr int BM = 32 * WM16, BN = 32 * WN16;
    __shared__ __align__(16) unsigned short Als[BM * 32];
    __shared__ __align__(16) unsigned short Bls[BN * 32];
    const int t = threadIdx.x;
    const int wave = t >> 6, lane = t & 63;
    const int wr = (wave >> 1) * (16 * WM16);
    const int wc = (wave & 1) * (16 * WN16);
    const int row0 = blockIdx.y * BM;
    const int col0 = blockIdx.x * BN;

    f4_t acc[WM16][WN16];
#pragma unroll
    for (int m = 0; m < WM16; m++)
#pragma unroll
        for (int n = 0; n < WN16; n++) { acc[m][n] = (f4_t){0.f, 0.f, 0.f, 0.f}; }

    const int lrow = lane & 15, kg = lane >> 4;
    for (int kk = 0; kk < Kpad; kk += 32) {
        for (int i = t; i < BM * 4; i += 256) {
            int r = i >> 2, slot = i & 3;
            uint4 v = *(const uint4*)&A[(size_t)(row0 + r) * Kpad + kk + slot * 8];
            *(uint4*)&Als[r * 32 + ((slot ^ (r & 3) ^ ((r >> 2) & 3)) * 8)] = v;
        }
        for (int i = t; i < BN * 4; i += 256) {
            int r = i >> 2, slot = i & 3;
            uint4 v = *(const uint4*)&BT[(size_t)(col0 + r) * Kpad + kk + slot * 8];
            *(uint4*)&Bls[r * 32 + ((slot ^ (r & 3) ^ ((r >> 2) & 3)) * 8)] = v;
        }
        __syncthreads();
        frag_t af[WM16], bfr[WN16];
#pragma unroll
        for (int m = 0; m < WM16; m++) {
            int r = wr + m * 16 + lrow;
            af[m] = *(frag_t*)&Als[r * 32 + ((kg ^ (r & 3) ^ ((r >> 2) & 3)) * 8)];
        }
#pragma unroll
        for (int n = 0; n < WN16; n++) {
            int r = wc + n * 16 + lrow;
            bfr[n] = *(frag_t*)&Bls[r * 32 + ((kg ^ (r & 3) ^ ((r >> 2) & 3)) * 8)];
        }
#pragma unroll
        for (int m = 0; m < WM16; m++)
#pragma unroll
            for (int n = 0; n < WN16; n++)
                acc[m][n] = __builtin_amdgcn_mfma_f32_16x16x32_bf16(af[m], bfr[n], acc[m][n], 0, 0, 0);
        __syncthreads();
    }

#pragma unroll
    for (int m = 0; m < WM16; m++) {
#pragma unroll
        for (int n = 0; n < WN16; n++) {
            int col = col0 + wc + n * 16 + lrow;
            float bv = HAS_BIAS ? bias[col] : 0.f;
#pragma unroll
            for (int r = 0; r < 4; r++) {
                int row = row0 + wr + m * 16 + kg * 4 + r;
                float v = acc[m][n][r] + bv;
                if (ACT) v = fmaxf(v, 0.f);
                if (OUT_MODE == 0)      ((float*)C)[(size_t)row * N + col] = v;
                else if (OUT_MODE == 1) ((unsigned short*)C)[(size_t)row * N + col] = f2bf(v);
                else {
                    if (col < 10)                  esp[row * 10 + col] = v;
                    else if (col >= 16 && col < 26) edp[row * 10 + (col - 16)] = v;
                }
            }
        }
    }
}

// ================= mega weight-prep =================
#define S0 1572864   // xb: 16384*96
#define S1 122880    // W1T: 1280*96
#define S2 163840    // W2T: 128*1280
#define S3 1966080   // Wf1T: 2048*960
#define S4 1048576   // Wf2T: 512*2048
#define S5 65536     // Wf3T: 128*512
#define S6 16384     // WgT: 128*128
#define PREP_TOTAL (S0+S1+S2+S3+S4+S5+S6)   // 4956160 = 19360*256

__global__ void prep_weights(const float* __restrict__ x,  const float* __restrict__ W1,
                             const float* __restrict__ W2, const float* __restrict__ Wf1,
                             const float* __restrict__ Wf2, const float* __restrict__ Wf3,
                             const float* __restrict__ Wg,
                             unsigned short* __restrict__ xb,  unsigned short* __restrict__ W1T,
                             unsigned short* __restrict__ W2T, unsigned short* __restrict__ Wf1T,
                             unsigned short* __restrict__ Wf2T, unsigned short* __restrict__ Wf3T,
                             unsigned short* __restrict__ WgT)
{
    int i = blockIdx.x * 256 + threadIdx.x;
    if (i < S0) { int r = i / 96, k = i % 96;
        xb[i] = (k < F_INPUT) ? f2bf(x[r * F_INPUT + k]) : 0; return; }
    i -= S0;
    if (i < S1) { int n = i / 96, k = i % 96;
        W1T[i] = (k < F_INPUT) ? f2bf(W1[(size_t)k * F1 + n]) : 0; return; }
    i -= S1;
    if (i < S2) { int n = i / 1280, k = i % 1280;
        W2T[i] = f2bf(W2[(size_t)k * HID + n]); return; }
    i -= S2;
    if (i < S3) { int n = i / 960, k = i % 960;
        Wf1T[i] = (k < F_CELL) ? f2bf(Wf1[(size_t)k * 2048 + n]) : 0; return; }
    i -= S3;
    if (i < S4) { int n = i / 2048, k = i % 2048;
        Wf2T[i] = f2bf(Wf2[(size_t)k * 512 + n]); return; }
    i -= S4;
    if (i < S5) { int n = i / 512, k = i % 512;
        Wf3T[i] = f2bf(Wf3[(size_t)k * HID + n]); return; }
    i -= S5;
    { int n = i / 128, k = i % 128;
        WgT[i] = f2bf(Wg[(size_t)k * HID + n]); }
}

// F1T [32,96] bf16: row r = sd*16+h holds fold of W1 with a_{s|d}[h]; wave per entry.
__global__ void fold1_w(const float* __restrict__ W1, const float* __restrict__ as_,
                        const float* __restrict__ ad_, unsigned short* __restrict__ F1T)
{
    int idx = blockIdx.x * 4 + (threadIdx.x >> 6);   // 0..3071
    int l = threadIdx.x & 63;
    int r = idx / 96, k = idx % 96;
    int sd = r >> 4, h = r & 15;
    float p = 0.f;
    if (h < HEADS && k < F_INPUT) {
        const float* a = (sd ? ad_ : as_) + h * HID;
        float2 wv = *(const float2*)&W1[(size_t)k * F1 + h * HID + 2 * l];
        float2 av = *(const float2*)&a[2 * l];
        p = wv.x * av.x + wv.y * av.y;
#pragma unroll
        for (int o = 32; o > 0; o >>= 1) p += __shfl_xor(p, o);
    }
    if (l == 0) F1T[(size_t)r * 96 + k] = f2bf(p);
}

// ================= CSR build (by dst) =================
__global__ void hist_dst(const int* __restrict__ ei, int* __restrict__ counts)
{
    int e = blockIdx.x * blockDim.x + threadIdx.x;
    if (e >= ETOT) return;
    int dst = (e < E_EDGES) ? ei[E_EDGES + e] : (e - E_EDGES);
    atomicAdd(&counts[dst], 1);
}

__global__ void scan_counts(const int* __restrict__ counts,
                            int* __restrict__ row_start, int* __restrict__ cursor)
{
    __shared__ int part[256];
    int t = threadIdx.x;
    int base = t * 64;
    int sum = 0;
    for (int i = 0; i < 64; i++) sum += counts[base + i];
    part[t] = sum;
    __syncthreads();
    for (int o = 1; o < 256; o <<= 1) {
        int v = 0;
        if (t >= o) v = part[t - o];
        __syncthreads();
        part[t] += v;
        __syncthreads();
    }
    int run = (t == 0) ? 0 : part[t - 1];
    for (int i = 0; i < 64; i++) {
        row_start[base + i] = run;
        cursor[base + i] = run;
        run += counts[base + i];
    }
    if (t == 255) row_start[N_NODES] = run;
}

__global__ void scatter_csr(const int* __restrict__ ei, int* __restrict__ cursor,
                            int* __restrict__ csr_src)
{
    int e = blockIdx.x * blockDim.x + threadIdx.x;
    if (e >= ETOT) return;
    int src, dst;
    if (e < E_EDGES) { src = ei[e]; dst = ei[E_EDGES + e]; } else { src = dst = e - E_EDGES; }
    int pos = atomicAdd(&cursor[dst], 1);
    csr_src[pos] = src;
}

// ================= layer-2 attention coefficients (wave per node, bf16 H2) =====
__global__ void attn_coef2(const unsigned short* __restrict__ H2,
                           const float* __restrict__ as_, const float* __restrict__ ad_,
                           float* __restrict__ es, float* __restrict__ ed)
{
    int n = blockIdx.x * 4 + (threadIdx.x >> 6);
    int l = threadIdx.x & 63;
    unsigned p = *(const unsigned*)&H2[(size_t)n * HID + 2 * l];
    float h0 = bf2f((unsigned short)(p & 0xffffu));
    float h1 = bf2f((unsigned short)(p >> 16));
    float2 av = *(const float2*)&as_[2 * l];
    float2 dv = *(const float2*)&ad_[2 * l];
    float vs = h0 * av.x + h1 * av.y;
    float vd = h0 * dv.x + h1 * dv.y;
#pragma unroll
    for (int o = 32; o > 0; o >>= 1) { vs += __shfl_xor(vs, o); vd += __shfl_xor(vd, o); }
    if (l == 0) { es[n] = vs; ed[n] = vd; }
}

// ================= GAT layer-1 aggregation: WAVE per dst, SINGLE PASS ==========
// No max subtraction: exp(e)/sum(exp(e)) is exact (|e| <~ 2 for this data dist,
// f32 exp range is +-88) and mathematically identical to the max-shifted form.
__global__ __launch_bounds__(256) void gat1_agg(
    const int* __restrict__ row_start, const int* __restrict__ csr_src,
    const unsigned short* __restrict__ H,
    const float* __restrict__ es, const float* __restrict__ ed,
    const float* __restrict__ b, unsigned short* __restrict__ xout)
{
    const int w = threadIdx.x >> 6, l = threadIdx.x & 63;
    const int n = blockIdx.x * 4 + w;
    const int rs = row_start[n];
    const int deg = row_start[n + 1] - rs;
    const int hi = l >> 4;

    __shared__ float w_lds[4][64][11];
    __shared__ int   src_lds[4][64];

    float edv[HEADS];
    const float* edp = ed + n * HEADS;
#pragma unroll
    for (int h = 0; h < HEADS; h++) edv[h] = edp[h];

    float acc[3][8];
#pragma unroll
    for (int s0 = 0; s0 < 3; s0++)
#pragma unroll
        for (int k = 0; k < 8; k++) acc[s0][k] = 0.f;
    float den[HEADS];
#pragma unroll
    for (int h = 0; h < HEADS; h++) den[h] = 0.f;

    for (int base = 0; base < deg; base += 64) {
        int e = base + l;
        int cnt = min(64, deg - base);
        float wv[HEADS];
        if (e < deg) {
            int s = csr_src[rs + e];
            src_lds[w][l] = s;
            const float* ep = es + s * HEADS;
#pragma unroll
            for (int h = 0; h < HEADS; h++) {
                float v = ep[h] + edv[h];
                v = (v >= 0.f) ? v : NEG_SLOPE * v;
                wv[h] = __expf(v);
            }
        } else {
#pragma unroll
            for (int h = 0; h < HEADS; h++) wv[h] = 0.f;
        }
#pragma unroll
        for (int h = 0; h < HEADS; h++) {
            den[h] += wv[h];
            w_lds[w][l][h] = wv[h];
        }
        asm volatile("" ::: "memory");

        for (int j = 0; j < cnt; j++) {
            int sj = src_lds[w][j];
            const unsigned short* hrow = H + (size_t)sj * F1;
#pragma unroll
            for (int slot = 0; slot < 3; slot++) {
                if (slot < 2 || l < 32) {
                    int c0 = slot * 512 + l * 8;
                    float wj = w_lds[w][j][slot * 4 + hi];
                    u16x8 v = *(const u16x8*)&hrow[c0];
#pragma unroll
                    for (int k = 0; k < 8; k++)
                        acc[slot][k] = fmaf(wj, bf2f((unsigned short)v[k]), acc[slot][k]);
                }
            }
        }
        asm volatile("" ::: "memory");
    }

#pragma unroll
    for (int h = 0; h < HEADS; h++)
#pragma unroll
        for (int o = 32; o > 0; o >>= 1) den[h] += __shfl_xor(den[h], o);

    unsigned short* orow = xout + (size_t)n * F1;
#pragma unroll
    for (int slot = 0; slot < 3; slot++) {
        if (slot < 2 || l < 32) {
            int c0 = slot * 512 + l * 8;
            float dh;
            if (slot == 2) dh = (hi & 1) ? den[9] : den[8];
            else dh = (hi == 0) ? den[slot * 4] : (hi == 1) ? den[slot * 4 + 1]
                    : (hi == 2) ? den[slot * 4 + 2] : den[slot * 4 + 3];
            float inv = 1.f / dh;
            float4 b0 = *(const float4*)&b[c0];
            float4 b1 = *(const float4*)&b[c0 + 4];
            float bb[8] = {b0.x, b0.y, b0.z, b0.w, b1.x, b1.y, b1.z, b1.w};
            u16x8 ov;
#pragma unroll
            for (int k = 0; k < 8; k++) {
                float v = acc[slot][k] * inv + bb[k];
                ov[k] = f2bf((v > 0.f) ? v : expm1f(v));
            }
            *(u16x8*)&orow[c0] = ov;
        }
    }
}

// ================= GAT layer-2 aggregation: WAVE per dst, SINGLE PASS ==========
__global__ __launch_bounds__(256) void gat2_agg(
    const int* __restrict__ row_start, const int* __restrict__ csr_src,
    const unsigned short* __restrict__ H2,
    const float* __restrict__ es, const float* __restrict__ ed,
    const float* __restrict__ b, float* __restrict__ xout)
{
    const int w = threadIdx.x >> 6, l = threadIdx.x & 63;
    const int n = blockIdx.x * 4 + w;
    const int rs = row_start[n];
    const int deg = row_start[n + 1] - rs;
    const float edv = ed[n];

    float2 acc = {0.f, 0.f};
    float den = 0.f;
    for (int base = 0; base < deg; base += 64) {
        int e = base + l;
        int cnt = min(64, deg - base);
        int s = 0;
        float wv = 0.f;
        if (e < deg) {
            s = csr_src[rs + e];
            float v = es[s] + edv;
            v = (v >= 0.f) ? v : NEG_SLOPE * v;
            wv = __expf(v);
        }
        den += wv;
        for (int j = 0; j < cnt; j++) {
            float wj = __shfl(wv, j);
            int   sj = __shfl(s, j);
            unsigned hp = *(const unsigned*)&H2[(size_t)sj * HID + 2 * l];
            acc.x = fmaf(wj, bf2f((unsigned short)(hp & 0xffffu)), acc.x);
            acc.y = fmaf(wj, bf2f((unsigned short)(hp >> 16)), acc.y);
        }
    }
#pragma unroll
    for (int o = 32; o > 0; o >>= 1) den += __shfl_xor(den, o);

    float inv = 1.f / den;
    float2 bv = *(const float2*)&b[2 * l];
    float v0 = acc.x * inv + bv.x;
    float v1 = acc.y * inv + bv.y;
    float2 ov;
    ov.x = (v0 > 0.f) ? v0 : expm1f(v0);
    ov.y = (v1 > 0.f) ? v1 : expm1f(v1);
    *(float2*)(xout + (size_t)n * HID + 2 * l) = ov;
}

// ================= pool / cell / final =================
__global__ void pool_max(const float* __restrict__ x2, const int* __restrict__ batch,
                         unsigned* __restrict__ pk)
{
    int idx = blockIdx.x * blockDim.x + threadIdx.x;
    if (idx >= N_NODES * HID) return;
    int n = idx >> 7, c = idx & 127;
    atomicMax(&pk[batch[n] * HID + c], fkey(x2[idx]));
}

__global__ void decode_keys_bf16(const unsigned* __restrict__ pk,
                                 unsigned short* __restrict__ outb, int count)
{
    int i = blockIdx.x * blockDim.x + threadIdx.x;
    if (i < count) outb[i] = f2bf(funkey(pk[i]));
}

__global__ void cell_norm(const float* __restrict__ cell, unsigned short* __restrict__ celln)
{
    int b = blockIdx.x;     // 256 rows
    int t = threadIdx.x;    // 256 threads
    __shared__ float red[256];
    float s = 0.f;
    for (int c = t; c < F_CELL; c += 256) { float v = cell[(size_t)b * F_CELL + c]; s += v * v; }
    red[t] = s; __syncthreads();
    for (int o = 128; o > 0; o >>= 1) { if (t < o) red[t] += red[t + o]; __syncthreads(); }
    float inv = 1.f / fmaxf(sqrtf(red[0]), 1e-12f);
    for (int c = t; c < KPADC; c += 256) {
        float v = (c < F_CELL) ? cell[(size_t)b * F_CELL + c] * inv : 0.f;
        celln[(size_t)b * KPADC + c] = f2bf(v);
    }
}

__global__ void final_out(const float* __restrict__ xg, const float* __restrict__ xc3,
                          const float* __restrict__ Wo, const float* __restrict__ bo,
                          float* __restrict__ out)
{
    int b = blockIdx.x, t = threadIdx.x;   // 128 threads
    float v = xc3[b * HID + t];
    float p0 = v * Wo[t * 2], p1 = v * Wo[t * 2 + 1];
    __shared__ float s[4];
#pragma unroll
    for (int o = 32; o > 0; o >>= 1) { p0 += __shfl_down(p0, o); p1 += __shfl_down(p1, o); }
    if ((t & 63) == 0) { s[(t >> 6) * 2] = p0; s[(t >> 6) * 2 + 1] = p1; }
    __syncthreads();
    out[b * 130 + t] = xg[b * HID + t];
    if (t == 0) {
        out[b * 130 + 128] = s[0] + s[2] + bo[0];
        out[b * 130 + 129] = s[1] + s[3] + bo[1];
    }
}

extern "C" void kernel_launch(void* const* d_in, const int* in_sizes, int n_in,
                              void* d_out, int out_size, void* d_ws, size_t ws_size,
                              hipStream_t stream)
{
    const float* x    = (const float*)d_in[0];
    const int*   ei   = (const int*)d_in[1];
    const int*   batch= (const int*)d_in[2];
    const float* cell = (const float*)d_in[3];
    const float* W1   = (const float*)d_in[4];
    const float* as1  = (const float*)d_in[5];
    const float* ad1  = (const float*)d_in[6];
    const float* b1   = (const float*)d_in[7];
    const float* W2   = (const float*)d_in[8];
    const float* as2  = (const float*)d_in[9];
    const float* ad2  = (const float*)d_in[10];
    const float* b2   = (const float*)d_in[11];
    const float* Wg   = (const float*)d_in[12];
    const float* bg   = (const float*)d_in[13];
    const float* Wf1  = (const float*)d_in[14];
    const float* bf1  = (const float*)d_in[15];
    const float* Wf2  = (const float*)d_in[16];
    const float* bf2  = (const float*)d_in[17];
    const float* Wf3  = (const float*)d_in[18];
    const float* bf3  = (const float*)d_in[19];
    const float* Wo   = (const float*)d_in[20];
    const float* bo   = (const float*)d_in[21];
    float* out = (float*)d_out;

    char* w = (char*)d_ws;
    auto alloc = [&](size_t bytes) { char* p = w; w += (bytes + 255) & ~(size_t)255; return p; };
    unsigned short* xb   = (unsigned short*)alloc((size_t)N_NODES * KPAD1 * 2);
    unsigned short* W1T  = (unsigned short*)alloc((size_t)F1 * KPAD1 * 2);
    unsigned short* F1T  = (unsigned short*)alloc((size_t)32 * KPAD1 * 2);
    unsigned short* H1   = (unsigned short*)alloc((size_t)N_NODES * F1 * 2);      // 42 MB
    unsigned short* x1   = (unsigned short*)alloc((size_t)N_NODES * F1 * 2);      // 42 MB
    unsigned short* W2T  = (unsigned short*)alloc((size_t)HID * F1 * 2);
    unsigned short* H2   = (unsigned short*)alloc((size_t)N_NODES * HID * 2);     // 4.2 MB
    float*    es1  = (float*)alloc((size_t)N_NODES * HEADS * 4);
    float*    ed1  = (float*)alloc((size_t)N_NODES * HEADS * 4);
    float*    es2  = (float*)alloc((size_t)N_NODES * 4);
    float*    ed2  = (float*)alloc((size_t)N_NODES * 4);
    float*    x2   = (float*)alloc((size_t)N_NODES * HID * 4);
    int*      counts    = (int*)alloc((size_t)N_NODES * 4);
    int*      row_start = (int*)alloc((size_t)(N_NODES + 1) * 4);
    int*      cursor    = (int*)alloc((size_t)N_NODES * 4);
    int*      csr_src   = (int*)alloc((size_t)ETOT * 4);
    unsigned* pk   = (unsigned*)alloc((size_t)BGRAPH * HID * 4);
    unsigned short* pooledb = (unsigned short*)alloc((size_t)BGRAPH * HID * 2);
    unsigned short* WgT  = (unsigned short*)alloc((size_t)HID * HID * 2);
    float*    xg   = (float*)alloc((size_t)BGRAPH * HID * 4);
    unsigned short* celln = (unsigned short*)alloc((size_t)BGRAPH * KPADC * 2);
    unsigned short* Wf1T = (unsigned short*)alloc((size_t)2048 * KPADC * 2);
    unsigned short* Wf2T = (unsigned short*)alloc((size_t)512 * 2048 * 2);
    unsigned short* Wf3T = (unsigned short*)alloc((size_t)HID * 512 * 2);
    unsigned short* xc1b = (unsigned short*)alloc((size_t)BGRAPH * 2048 * 2);
    unsigned short* xc2b = (unsigned short*)alloc((size_t)BGRAPH * 512 * 2);
    float*    xc3  = (float*)alloc((size_t)BGRAPH * HID * 4);

    hipMemsetAsync(counts, 0, (size_t)N_NODES * 4, stream);
    hipMemsetAsync(pk,     0, (size_t)BGRAPH * HID * 4, stream);

    dim3 b256(256);
    const int egrid = (ETOT + 255) / 256;

    // ---- weight prep ----
    prep_weights<<<PREP_TOTAL / 256, b256, 0, stream>>>(x, W1, W2, Wf1, Wf2, Wf3, Wg,
                                                        xb, W1T, W2T, Wf1T, Wf2T, Wf3T, WgT);
    fold1_w<<<32 * 96 / 4, b256, 0, stream>>>(W1, as1, ad1, F1T);

    // ---- CSR build ----
    hist_dst<<<egrid, b256, 0, stream>>>(ei, counts);
    scan_counts<<<1, b256, 0, stream>>>(counts, row_start, cursor);
    scatter_csr<<<egrid, b256, 0, stream>>>(ei, cursor, csr_src);

    // ---- GAT layer 1 ----
    mfma_gemm<4, 4, 1, 0, 0><<<dim3(F1 / 128, N_NODES / 128), b256, 0, stream>>>(
        xb, W1T, nullptr, H1, nullptr, nullptr, N_NODES, F1, KPAD1);
    mfma_gemm<4, 1, 2, 0, 0><<<dim3(1, N_NODES / 128), b256, 0, stream>>>(
        xb, F1T, nullptr, nullptr, es1, ed1, N_NODES, 32, KPAD1);
    gat1_agg<<<N_NODES / 4, b256, 0, stream>>>(row_start, csr_src, H1, es1, ed1, b1, x1);

    // ---- GAT layer 2 (BM=32 -> 512 blocks, 2/CU) ----
    mfma_gemm<1, 4, 1, 0, 0><<<dim3(1, N_NODES / 32), b256, 0, stream>>>(
        x1, W2T, nullptr, H2, nullptr, nullptr, N_NODES, HID, F1);
    attn_coef2<<<N_NODES / 4, b256, 0, stream>>>(H2, as2, ad2, es2, ed2);
    gat2_agg<<<N_NODES / 4, b256, 0, stream>>>(row_start, csr_src, H2, es2, ed2, b2, x2);

    // ---- pool + drug fc ----
    pool_max<<<(N_NODES * HID + 255) / 256, b256, 0, stream>>>(x2, batch, pk);
    decode_keys_bf16<<<(BGRAPH * HID + 255) / 256, b256, 0, stream>>>(pk, pooledb, BGRAPH * HID);
    mfma_gemm<2, 2, 0, 1, 1><<<dim3(HID / 64, BGRAPH / 64), b256, 0, stream>>>(
        pooledb, WgT, bg, xg, nullptr, nullptr, BGRAPH, HID, HID);

    // ---- cell branch ----
    cell_norm<<<BGRAPH, b256, 0, stream>>>(cell, celln);
    mfma_gemm<2, 2, 1, 1, 1><<<dim3(2048 / 64, BGRAPH / 64), b256, 0, stream>>>(
        celln, Wf1T, bf1, xc1b, nullptr, nullptr, BGRAPH, 2048, KPADC);
    mfma_gemm<1, 2, 1, 1, 1><<<dim3(512 / 64, BGRAPH / 32), b256, 0, stream>>>(
        xc1b, Wf2T, bf2, xc2b, nullptr, nullptr, BGRAPH, 512, 2048);
    mfma_gemm<2, 2, 0, 1, 1><<<dim3(HID / 64, BGRAPH / 64), b256, 0, stream>>>(
        xc2b, Wf3T, bf3, xc3, nullptr, nullptr, BGRAPH, HID, 512);

    // ---- output head + concat ----
    final_out<<<BGRAPH, 128, 0, stream>>>(xg, xc3, Wo, bo, out);
}

// Round 8
// 250.719 us; speedup vs baseline: 1.3594x; 1.1262x over previous
//
#include <hip/hip_runtime.h>
#include <hip/hip_bf16.h>
#include <math.h>

#define N_NODES 16384
#define E_EDGES 131072
#define ETOT (E_EDGES + N_NODES)   // 147456 (self-loops appended)
#define BGRAPH 256
#define F_INPUT 78
#define KPAD1 96                   // F_INPUT padded to mult of 32
#define HID 128
#define HEADS 10
#define F1 (HEADS * HID)           // 1280
#define F_CELL 954
#define KPADC 960                  // F_CELL padded
#define NEG_SLOPE 0.2f

typedef __attribute__((ext_vector_type(8))) short frag_t;   // 8 bf16
typedef __attribute__((ext_vector_type(4))) float f4_t;

static __device__ __forceinline__ unsigned fkey(float f) {
    unsigned b = __float_as_uint(f);
    return (b & 0x80000000u) ? ~b : (b | 0x80000000u);
}
static __device__ __forceinline__ float funkey(unsigned k) {
    unsigned b = (k & 0x80000000u) ? (k ^ 0x80000000u) : ~k;
    return __uint_as_float(b);
}
static __device__ __forceinline__ unsigned short f2bf(float f) {
    __hip_bfloat16 h = __float2bfloat16(f);
    return *(unsigned short*)&h;
}
static __device__ __forceinline__ float bf2f(unsigned short u) {
    return __uint_as_float(((unsigned)u) << 16);
}

// ================= MFMA bf16 GEMM (strided + z-grouped) =================
// A [M,*] bf16 row-stride lda (+ z*za), BT [N,Kpad] (+ z*zb). C stride ldc (+ z*zc).
// OUT_MODE: 0 = f32, 1 = bf16, 2 = coef (cols 0..9 -> es, 16..25 -> ed).
// ACT: 0 none, 1 relu, 2 elu.
template<int WM16, int WN16, int OUT_MODE, int ACT, int HAS_BIAS>
__global__ __launch_bounds__(256) void mfma_gemm(
    const unsigned short* __restrict__ A, const unsigned short* __restrict__ BT,
    const float* __restrict__ bias, void* __restrict__ C,
    float* __restrict__ esp, float* __restrict__ edp,
    int M, int N, int Kpad, int lda, int ldc,
    int za, int zb, int zc, int zbias)
{
    constexpr int BM = 32 * WM16, BN = 32 * WN16;
    __shared__ __align__(16) unsigned short Als[BM * 32];
    __shared__ __align__(16) unsigned short Bls[BN * 32];
    const int z = blockIdx.z;
    A  += (size_t)z * za;
    BT += (size_t)z * zb;
    const int t = threadIdx.x;
    const int wave = t >> 6, lane = t & 63;
    const int wr = (wave >> 1) * (16 * WM16);
    const int wc = (wave & 1) * (16 * WN16);
    const int row0 = blockIdx.y * BM;
    const int col0 = blockIdx.x * BN;

    f4_t acc[WM16][WN16];
#pragma unroll
    for (int m = 0; m < WM16; m++)
#pragma unroll
        for (int n = 0; n < WN16; n++) { acc[m][n] = (f4_t){0.f, 0.f, 0.f, 0.f}; }

    const int lrow = lane & 15, kg = lane >> 4;
    for (int kk = 0; kk < Kpad; kk += 32) {
        for (int i = t; i < BM * 4; i += 256) {
            int r = i >> 2, slot = i & 3;
            uint4 v = *(const uint4*)&A[(size_t)(row0 + r) * lda + kk + slot * 8];
            *(uint4*)&Als[r * 32 + ((slot ^ (r & 3) ^ ((r >> 2) & 3)) * 8)] = v;
        }
        for (int i = t; i < BN * 4; i += 256) {
            int r = i >> 2, slot = i & 3;
            uint4 v = *(const uint4*)&BT[(size_t)(col0 + r) * Kpad + kk + slot * 8];
            *(uint4*)&Bls[r * 32 + ((slot ^ (r & 3) ^ ((r >> 2) & 3)) * 8)] = v;
        }
        __syncthreads();
        frag_t af[WM16], bfr[WN16];
#pragma unroll
        for (int m = 0; m < WM16; m++) {
            int r = wr + m * 16 + lrow;
            af[m] = *(frag_t*)&Als[r * 32 + ((kg ^ (r & 3) ^ ((r >> 2) & 3)) * 8)];
        }
#pragma unroll
        for (int n = 0; n < WN16; n++) {
            int r = wc + n * 16 + lrow;
            bfr[n] = *(frag_t*)&Bls[r * 32 + ((kg ^ (r & 3) ^ ((r >> 2) & 3)) * 8)];
        }
#pragma unroll
        for (int m = 0; m < WM16; m++)
#pragma unroll
            for (int n = 0; n < WN16; n++)
                acc[m][n] = __builtin_amdgcn_mfma_f32_16x16x32_bf16(af[m], bfr[n], acc[m][n], 0, 0, 0);
        __syncthreads();
    }

#pragma unroll
    for (int m = 0; m < WM16; m++) {
#pragma unroll
        for (int n = 0; n < WN16; n++) {
            int col = col0 + wc + n * 16 + lrow;
            float bv = HAS_BIAS ? bias[z * zbias + col] : 0.f;
#pragma unroll
            for (int r = 0; r < 4; r++) {
                int row = row0 + wr + m * 16 + kg * 4 + r;
                float v = acc[m][n][r] + bv;
                if (ACT == 1) v = fmaxf(v, 0.f);
                if (ACT == 2) v = (v > 0.f) ? v : expm1f(v);
                size_t ci = (size_t)row * ldc + (size_t)z * zc + col;
                if (OUT_MODE == 0)      ((float*)C)[ci] = v;
                else if (OUT_MODE == 1) ((unsigned short*)C)[ci] = f2bf(v);
                else {
                    if (col < 10)                  esp[row * 10 + col] = v;
                    else if (col >= 16 && col < 26) edp[row * 10 + (col - 16)] = v;
                }
            }
        }
    }
}

// ================= mega weight-prep =================
#define S0 1572864   // xb: 16384*96
#define S1 122880    // W1T: 1280*96
#define S2 163840    // W2T: 128*1280
#define S3 1966080   // Wf1T: 2048*960
#define S4 1048576   // Wf2T: 512*2048
#define S5 65536     // Wf3T: 128*512
#define S6 16384     // WgT: 128*128
#define PREP_TOTAL (S0+S1+S2+S3+S4+S5+S6)   // 4956160 = 19360*256

__global__ void prep_weights(const float* __restrict__ x,  const float* __restrict__ W1,
                             const float* __restrict__ W2, const float* __restrict__ Wf1,
                             const float* __restrict__ Wf2, const float* __restrict__ Wf3,
                             const float* __restrict__ Wg,
                             unsigned short* __restrict__ xb,  unsigned short* __restrict__ W1T,
                             unsigned short* __restrict__ W2T, unsigned short* __restrict__ Wf1T,
                             unsigned short* __restrict__ Wf2T, unsigned short* __restrict__ Wf3T,
                             unsigned short* __restrict__ WgT)
{
    int i = blockIdx.x * 256 + threadIdx.x;
    if (i < S0) { int r = i / 96, k = i % 96;
        xb[i] = (k < F_INPUT) ? f2bf(x[r * F_INPUT + k]) : 0; return; }
    i -= S0;
    if (i < S1) { int n = i / 96, k = i % 96;
        W1T[i] = (k < F_INPUT) ? f2bf(W1[(size_t)k * F1 + n]) : 0; return; }
    i -= S1;
    if (i < S2) { int n = i / 1280, k = i % 1280;
        W2T[i] = f2bf(W2[(size_t)k * HID + n]); return; }
    i -= S2;
    if (i < S3) { int n = i / 960, k = i % 960;
        Wf1T[i] = (k < F_CELL) ? f2bf(Wf1[(size_t)k * 2048 + n]) : 0; return; }
    i -= S3;
    if (i < S4) { int n = i / 2048, k = i % 2048;
        Wf2T[i] = f2bf(Wf2[(size_t)k * 512 + n]); return; }
    i -= S4;
    if (i < S5) { int n = i / 512, k = i % 512;
        Wf3T[i] = f2bf(Wf3[(size_t)k * HID + n]); return; }
    i -= S5;
    { int n = i / 128, k = i % 128;
        WgT[i] = f2bf(Wg[(size_t)k * HID + n]); }
}

// F1T [32,96] bf16: row r = sd*16+h holds fold of W1 with a_{s|d}[h]; wave per entry.
__global__ void fold1_w(const float* __restrict__ W1, const float* __restrict__ as_,
                        const float* __restrict__ ad_, unsigned short* __restrict__ F1T)
{
    int idx = blockIdx.x * 4 + (threadIdx.x >> 6);   // 0..3071
    int l = threadIdx.x & 63;
    int r = idx / 96, k = idx % 96;
    int sd = r >> 4, h = r & 15;
    float p = 0.f;
    if (h < HEADS && k < F_INPUT) {
        const float* a = (sd ? ad_ : as_) + h * HID;
        float2 wv = *(const float2*)&W1[(size_t)k * F1 + h * HID + 2 * l];
        float2 av = *(const float2*)&a[2 * l];
        p = wv.x * av.x + wv.y * av.y;
#pragma unroll
        for (int o = 32; o > 0; o >>= 1) p += __shfl_xor(p, o);
    }
    if (l == 0) F1T[(size_t)r * 96 + k] = f2bf(p);
}

// ================= CSR build (by dst) =================
__global__ void hist_dst(const int* __restrict__ ei, int* __restrict__ counts)
{
    int e = blockIdx.x * blockDim.x + threadIdx.x;
    if (e >= ETOT) return;
    int dst = (e < E_EDGES) ? ei[E_EDGES + e] : (e - E_EDGES);
    atomicAdd(&counts[dst], 1);
}

__global__ void scan_counts(const int* __restrict__ counts,
                            int* __restrict__ row_start, int* __restrict__ cursor)
{
    __shared__ int part[256];
    int t = threadIdx.x;
    int base = t * 64;
    int sum = 0;
    for (int i = 0; i < 64; i++) sum += counts[base + i];
    part[t] = sum;
    __syncthreads();
    for (int o = 1; o < 256; o <<= 1) {
        int v = 0;
        if (t >= o) v = part[t - o];
        __syncthreads();
        part[t] += v;
        __syncthreads();
    }
    int run = (t == 0) ? 0 : part[t - 1];
    for (int i = 0; i < 64; i++) {
        row_start[base + i] = run;
        cursor[base + i] = run;
        run += counts[base + i];
    }
    if (t == 255) row_start[N_NODES] = run;
}

__global__ void scatter_csr(const int* __restrict__ ei, int* __restrict__ cursor,
                            int* __restrict__ csr_src)
{
    int e = blockIdx.x * blockDim.x + threadIdx.x;
    if (e >= ETOT) return;
    int src, dst;
    if (e < E_EDGES) { src = ei[e]; dst = ei[E_EDGES + e]; } else { src = dst = e - E_EDGES; }
    int pos = atomicAdd(&cursor[dst], 1);
    csr_src[pos] = src;
}

// ================= layer-2 attention coefficients (wave per node, bf16 H2) =====
__global__ void attn_coef2(const unsigned short* __restrict__ H2,
                           const float* __restrict__ as_, const float* __restrict__ ad_,
                           float* __restrict__ es, float* __restrict__ ed)
{
    int n = blockIdx.x * 4 + (threadIdx.x >> 6);
    int l = threadIdx.x & 63;
    unsigned p = *(const unsigned*)&H2[(size_t)n * HID + 2 * l];
    float h0 = bf2f((unsigned short)(p & 0xffffu));
    float h1 = bf2f((unsigned short)(p >> 16));
    float2 av = *(const float2*)&as_[2 * l];
    float2 dv = *(const float2*)&ad_[2 * l];
    float vs = h0 * av.x + h1 * av.y;
    float vd = h0 * dv.x + h1 * dv.y;
#pragma unroll
    for (int o = 32; o > 0; o >>= 1) { vs += __shfl_xor(vs, o); vd += __shfl_xor(vd, o); }
    if (l == 0) { es[n] = vs; ed[n] = vd; }
}

// ================= GAT layer-1 aggregation over RAW x (96 bf16 per row) ========
// agg[n,h,:] = (sum_e w_e[h] * x_src[:]) / den[h]  -> bf16 [N,960]
// (W1 applied afterwards by a grouped MFMA GEMM: linearity of the transform.)
__global__ __launch_bounds__(256) void gat1_agg(
    const int* __restrict__ row_start, const int* __restrict__ csr_src,
    const unsigned* __restrict__ xb32,          // [N,48] u32 = 96 bf16
    const float* __restrict__ es, const float* __restrict__ ed,
    unsigned* __restrict__ aggb)                // [N,480] u32 = 960 bf16
{
    const int w = threadIdx.x >> 6, l = threadIdx.x & 63;
    const int n = blockIdx.x * 4 + w;
    const int rs = row_start[n];
    const int deg = row_start[n + 1] - rs;

    __shared__ __align__(16) float w_lds[4][64][12];
    __shared__ int src_lds[4][64];

    float edv[HEADS];
    const float* edp = ed + n * HEADS;
#pragma unroll
    for (int h = 0; h < HEADS; h++) edv[h] = edp[h];

    float acc0[HEADS], acc1[HEADS], den[HEADS];
#pragma unroll
    for (int h = 0; h < HEADS; h++) { acc0[h] = 0.f; acc1[h] = 0.f; den[h] = 0.f; }

    for (int base = 0; base < deg; base += 64) {
        int e = base + l;
        int cnt = min(64, deg - base);
        float wv[HEADS];
        if (e < deg) {
            int s = csr_src[rs + e];
            src_lds[w][l] = s;
            const float* ep = es + s * HEADS;
#pragma unroll
            for (int h = 0; h < HEADS; h++) {
                float v = ep[h] + edv[h];
                v = (v >= 0.f) ? v : NEG_SLOPE * v;
                wv[h] = __expf(v);
            }
        } else {
#pragma unroll
            for (int h = 0; h < HEADS; h++) wv[h] = 0.f;
        }
#pragma unroll
        for (int h = 0; h < HEADS; h++) {
            den[h] += wv[h];
            w_lds[w][l][h] = wv[h];
        }
        asm volatile("" ::: "memory");

        for (int j = 0; j < cnt; j++) {
            int sj = src_lds[w][j];
            unsigned xv = 0;
            if (l < 48) xv = xb32[(size_t)sj * 48 + l];
            float x0 = bf2f((unsigned short)(xv & 0xffffu));
            float x1v = bf2f((unsigned short)(xv >> 16));
            float4 wa = *(const float4*)&w_lds[w][j][0];
            float4 wb = *(const float4*)&w_lds[w][j][4];
            float2 wcv = *(const float2*)&w_lds[w][j][8];
            float ww[HEADS] = {wa.x, wa.y, wa.z, wa.w, wb.x, wb.y, wb.z, wb.w, wcv.x, wcv.y};
#pragma unroll
            for (int h = 0; h < HEADS; h++) {
                acc0[h] = fmaf(ww[h], x0, acc0[h]);
                acc1[h] = fmaf(ww[h], x1v, acc1[h]);
            }
        }
        asm volatile("" ::: "memory");
    }

#pragma unroll
    for (int h = 0; h < HEADS; h++)
#pragma unroll
        for (int o = 32; o > 0; o >>= 1) den[h] += __shfl_xor(den[h], o);

    if (l < 48) {
        unsigned* orow = aggb + (size_t)n * 480;
#pragma unroll
        for (int h = 0; h < HEADS; h++) {
            float inv = 1.f / den[h];
            unsigned lo = f2bf(acc0[h] * inv);
            unsigned hi = f2bf(acc1[h] * inv);
            orow[h * 48 + l] = lo | (hi << 16);
        }
    }
}

// ================= GAT layer-2 aggregation: WAVE per dst, single pass ==========
__global__ __launch_bounds__(256) void gat2_agg(
    const int* __restrict__ row_start, const int* __restrict__ csr_src,
    const unsigned short* __restrict__ H2,
    const float* __restrict__ es, const float* __restrict__ ed,
    const float* __restrict__ b, float* __restrict__ xout)
{
    const int w = threadIdx.x >> 6, l = threadIdx.x & 63;
    const int n = blockIdx.x * 4 + w;
    const int rs = row_start[n];
    const int deg = row_start[n + 1] - rs;
    const float edv = ed[n];

    float2 acc = {0.f, 0.f};
    float den = 0.f;
    for (int base = 0; base < deg; base += 64) {
        int e = base + l;
        int cnt = min(64, deg - base);
        int s = 0;
        float wv = 0.f;
        if (e < deg) {
            s = csr_src[rs + e];
            float v = es[s] + edv;
            v = (v >= 0.f) ? v : NEG_SLOPE * v;
            wv = __expf(v);
        }
        den += wv;
        for (int j = 0; j < cnt; j++) {
            float wj = __shfl(wv, j);
            int   sj = __shfl(s, j);
            unsigned hp = *(const unsigned*)&H2[(size_t)sj * HID + 2 * l];
            acc.x = fmaf(wj, bf2f((unsigned short)(hp & 0xffffu)), acc.x);
            acc.y = fmaf(wj, bf2f((unsigned short)(hp >> 16)), acc.y);
        }
    }
#pragma unroll
    for (int o = 32; o > 0; o >>= 1) den += __shfl_xor(den, o);

    float inv = 1.f / den;
    float2 bv = *(const float2*)&b[2 * l];
    float v0 = acc.x * inv + bv.x;
    float v1 = acc.y * inv + bv.y;
    float2 ov;
    ov.x = (v0 > 0.f) ? v0 : expm1f(v0);
    ov.y = (v1 > 0.f) ? v1 : expm1f(v1);
    *(float2*)(xout + (size_t)n * HID + 2 * l) = ov;
}

// ================= pool / cell / final =================
__global__ void pool_max(const float* __restrict__ x2, const int* __restrict__ batch,
                         unsigned* __restrict__ pk)
{
    int idx = blockIdx.x * blockDim.x + threadIdx.x;
    if (idx >= N_NODES * HID) return;
    int n = idx >> 7, c = idx & 127;
    atomicMax(&pk[batch[n] * HID + c], fkey(x2[idx]));
}

__global__ void decode_keys_bf16(const unsigned* __restrict__ pk,
                                 unsigned short* __restrict__ outb, int count)
{
    int i = blockIdx.x * blockDim.x + threadIdx.x;
    if (i < count) outb[i] = f2bf(funkey(pk[i]));
}

__global__ void cell_norm(const float* __restrict__ cell, unsigned short* __restrict__ celln)
{
    int b = blockIdx.x;     // 256 rows
    int t = threadIdx.x;    // 256 threads
    __shared__ float red[256];
    float s = 0.f;
    for (int c = t; c < F_CELL; c += 256) { float v = cell[(size_t)b * F_CELL + c]; s += v * v; }
    red[t] = s; __syncthreads();
    for (int o = 128; o > 0; o >>= 1) { if (t < o) red[t] += red[t + o]; __syncthreads(); }
    float inv = 1.f / fmaxf(sqrtf(red[0]), 1e-12f);
    for (int c = t; c < KPADC; c += 256) {
        float v = (c < F_CELL) ? cell[(size_t)b * F_CELL + c] * inv : 0.f;
        celln[(size_t)b * KPADC + c] = f2bf(v);
    }
}

__global__ void final_out(const float* __restrict__ xg, const float* __restrict__ xc3,
                          const float* __restrict__ Wo, const float* __restrict__ bo,
                          float* __restrict__ out)
{
    int b = blockIdx.x, t = threadIdx.x;   // 128 threads
    float v = xc3[b * HID + t];
    float p0 = v * Wo[t * 2], p1 = v * Wo[t * 2 + 1];
    __shared__ float s[4];
#pragma unroll
    for (int o = 32; o > 0; o >>= 1) { p0 += __shfl_down(p0, o); p1 += __shfl_down(p1, o); }
    if ((t & 63) == 0) { s[(t >> 6) * 2] = p0; s[(t >> 6) * 2 + 1] = p1; }
    __syncthreads();
    out[b * 130 + t] = xg[b * HID + t];
    if (t == 0) {
        out[b * 130 + 128] = s[0] + s[2] + bo[0];
        out[b * 130 + 129] = s[1] + s[3] + bo[1];
    }
}

extern "C" void kernel_launch(void* const* d_in, const int* in_sizes, int n_in,
                              void* d_out, int out_size, void* d_ws, size_t ws_size,
                              hipStream_t stream)
{
    const float* x    = (const float*)d_in[0];
    const int*   ei   = (const int*)d_in[1];
    const int*   batch= (const int*)d_in[2];
    const float* cell = (const float*)d_in[3];
    const float* W1   = (const float*)d_in[4];
    const float* as1  = (const float*)d_in[5];
    const float* ad1  = (const float*)d_in[6];
    const float* b1   = (const float*)d_in[7];
    const float* W2   = (const float*)d_in[8];
    const float* as2  = (const float*)d_in[9];
    const float* ad2  = (const float*)d_in[10];
    const float* b2   = (const float*)d_in[11];
    const float* Wg   = (const float*)d_in[12];
    const float* bg   = (const float*)d_in[13];
    const float* Wf1  = (const float*)d_in[14];
    const float* bf1  = (const float*)d_in[15];
    const float* Wf2  = (const float*)d_in[16];
    const float* bf2  = (const float*)d_in[17];
    const float* Wf3  = (const float*)d_in[18];
    const float* bf3  = (const float*)d_in[19];
    const float* Wo   = (const float*)d_in[20];
    const float* bo   = (const float*)d_in[21];
    float* out = (float*)d_out;

    char* w = (char*)d_ws;
    auto alloc = [&](size_t bytes) { char* p = w; w += (bytes + 255) & ~(size_t)255; return p; };
    unsigned short* xb   = (unsigned short*)alloc((size_t)N_NODES * KPAD1 * 2);   // 3.1 MB
    unsigned short* W1T  = (unsigned short*)alloc((size_t)F1 * KPAD1 * 2);
    unsigned short* F1T  = (unsigned short*)alloc((size_t)32 * KPAD1 * 2);
    unsigned*       aggb = (unsigned*)alloc((size_t)N_NODES * 480 * 4);           // 31.5 MB
    unsigned short* x1   = (unsigned short*)alloc((size_t)N_NODES * F1 * 2);      // 42 MB
    unsigned short* W2T  = (unsigned short*)alloc((size_t)HID * F1 * 2);
    unsigned short* H2   = (unsigned short*)alloc((size_t)N_NODES * HID * 2);     // 4.2 MB
    float*    es1  = (float*)alloc((size_t)N_NODES * HEADS * 4);
    float*    ed1  = (float*)alloc((size_t)N_NODES * HEADS * 4);
    float*    es2  = (float*)alloc((size_t)N_NODES * 4);
    float*    ed2  = (float*)alloc((size_t)N_NODES * 4);
    float*    x2   = (float*)alloc((size_t)N_NODES * HID * 4);
    int*      counts    = (int*)alloc((size_t)N_NODES * 4);
    int*      row_start = (int*)alloc((size_t)(N_NODES + 1) * 4);
    int*      cursor    = (int*)alloc((size_t)N_NODES * 4);
    int*      csr_src   = (int*)alloc((size_t)ETOT * 4);
    unsigned* pk   = (unsigned*)alloc((size_t)BGRAPH * HID * 4);
    unsigned short* pooledb = (unsigned short*)alloc((size_t)BGRAPH * HID * 2);
    unsigned short* WgT  = (unsigned short*)alloc((size_t)HID * HID * 2);
    float*    xg   = (float*)alloc((size_t)BGRAPH * HID * 4);
    unsigned short* celln = (unsigned short*)alloc((size_t)BGRAPH * KPADC * 2);
    unsigned short* Wf1T = (unsigned short*)alloc((size_t)2048 * KPADC * 2);
    unsigned short* Wf2T = (unsigned short*)alloc((size_t)512 * 2048 * 2);
    unsigned short* Wf3T = (unsigned short*)alloc((size_t)HID * 512 * 2);
    unsigned short* xc1b = (unsigned short*)alloc((size_t)BGRAPH * 2048 * 2);
    unsigned short* xc2b = (unsigned short*)alloc((size_t)BGRAPH * 512 * 2);
    float*    xc3  = (float*)alloc((size_t)BGRAPH * HID * 4);

    hipMemsetAsync(counts, 0, (size_t)N_NODES * 4, stream);
    hipMemsetAsync(pk,     0, (size_t)BGRAPH * HID * 4, stream);

    dim3 b256(256);
    const int egrid = (ETOT + 255) / 256;

    // ---- weight prep ----
    prep_weights<<<PREP_TOTAL / 256, b256, 0, stream>>>(x, W1, W2, Wf1, Wf2, Wf3, Wg,
                                                        xb, W1T, W2T, Wf1T, Wf2T, Wf3T, WgT);
    fold1_w<<<32 * 96 / 4, b256, 0, stream>>>(W1, as1, ad1, F1T);

    // ---- CSR build ----
    hist_dst<<<egrid, b256, 0, stream>>>(ei, counts);
    scan_counts<<<1, b256, 0, stream>>>(counts, row_start, cursor);
    scatter_csr<<<egrid, b256, 0, stream>>>(ei, cursor, csr_src);

    // ---- GAT layer 1 ----
    // coefs: es1/ed1 = x @ folded-a
    mfma_gemm<4, 1, 2, 0, 0><<<dim3(1, N_NODES / 128), b256, 0, stream>>>(
        xb, F1T, nullptr, nullptr, es1, ed1, N_NODES, 32, KPAD1, KPAD1, 32, 0, 0, 0, 0);
    // aggregate raw x per head (13x less gather than aggregating H1)
    gat1_agg<<<N_NODES / 4, b256, 0, stream>>>(row_start, csr_src, (const unsigned*)xb,
                                               es1, ed1, aggb);
    // x1[:, h*128:(h+1)*128] = elu(agg[:,h,:] @ W1h + b1h)  -- grouped over z=head
    mfma_gemm<4, 4, 1, 2, 1><<<dim3(1, N_NODES / 128, HEADS), b256, 0, stream>>>(
        (const unsigned short*)aggb, W1T, b1, x1, nullptr, nullptr,
        N_NODES, HID, KPAD1, 960, F1, KPAD1, HID * KPAD1, HID, HID);

    // ---- GAT layer 2 ----
    mfma_gemm<1, 4, 1, 0, 0><<<dim3(1, N_NODES / 32), b256, 0, stream>>>(
        x1, W2T, nullptr, H2, nullptr, nullptr, N_NODES, HID, F1, F1, HID, 0, 0, 0, 0);
    attn_coef2<<<N_NODES / 4, b256, 0, stream>>>(H2, as2, ad2, es2, ed2);
    gat2_agg<<<N_NODES / 4, b256, 0, stream>>>(row_start, csr_src, H2, es2, ed2, b2, x2);

    // ---- pool + drug fc ----
    pool_max<<<(N_NODES * HID + 255) / 256, b256, 0, stream>>>(x2, batch, pk);
    decode_keys_bf16<<<(BGRAPH * HID + 255) / 256, b256, 0, stream>>>(pk, pooledb, BGRAPH * HID);
    mfma_gemm<2, 2, 0, 1, 1><<<dim3(HID / 64, BGRAPH / 64), b256, 0, stream>>>(
        pooledb, WgT, bg, xg, nullptr, nullptr, BGRAPH, HID, HID, HID, HID, 0, 0, 0, 0);

    // ---- cell branch ----
    cell_norm<<<BGRAPH, b256, 0, stream>>>(cell, celln);
    mfma_gemm<2, 2, 1, 1, 1><<<dim3(2048 / 64, BGRAPH / 64), b256, 0, stream>>>(
        celln, Wf1T, bf1, xc1b, nullptr, nullptr, BGRAPH, 2048, KPADC, KPADC, 2048, 0, 0, 0, 0);
    mfma_gemm<1, 2, 1, 1, 1><<<dim3(512 / 64, BGRAPH / 32), b256, 0, stream>>>(
        xc1b, Wf2T, bf2, xc2b, nullptr, nullptr, BGRAPH, 512, 2048, 2048, 512, 0, 0, 0, 0);
    mfma_gemm<2, 2, 0, 1, 1><<<dim3(HID / 64, BGRAPH / 64), b256, 0, stream>>>(
        xc2b, Wf3T, bf3, xc3, nullptr, nullptr, BGRAPH, HID, 512, 512, HID, 0, 0, 0, 0);

    // ---- output head + concat ----
    final_out<<<BGRAPH, 128, 0, stream>>>(xg, xc3, Wo, bo, out);
}